// Round 10
// baseline (283.874 us; speedup 1.0000x reference)
//
#include <hip/hip_runtime.h>

// B=64 batches, n=64 nodes/batch, H=128, epg=2048 edges/batch
#define KK 52
#define NKOUT 3328
#define NEG 0.01f

typedef __attribute__((ext_vector_type(8))) __bf16 bf16x8;
typedef __attribute__((ext_vector_type(16))) float floatx16;

__device__ __forceinline__ float lrelu(float v){ return v > 0.f ? v : NEG*v; }

// LDS layout for MFMA chunks: row pitch 40 bf16 (80B); XOR swizzle on 16B chunks
#define SW(r, ko) ((r)*40 + ((ko) ^ ((((r)>>3)&3) << 3)))

__device__ __forceinline__ void split_store8(const float* vv, __bf16* P0, __bf16* P1, __bf16* P2, int addr){
  bf16x8 p1, p2, p3;
  #pragma unroll
  for (int j = 0; j < 8; j++){
    __bf16 b1 = (__bf16)vv[j];
    float r1 = vv[j] - (float)b1;
    __bf16 b2 = (__bf16)r1;
    float r2 = r1 - (float)b2;
    p1[j] = b1; p2[j] = b2; p3[j] = (__bf16)r2;
  }
  *(bf16x8*)(P0 + addr) = p1;
  *(bf16x8*)(P1 + addr) = p2;
  *(bf16x8*)(P2 + addr) = p3;
}

__device__ __forceinline__ void mfma6(const __bf16* A0, const __bf16* A1, const __bf16* A2,
                                      const __bf16* B0, const __bf16* B1, const __bf16* B2,
                                      int aoff, int boff, floatx16* acc){
  bf16x8 a1 = *(const bf16x8*)(A0 + aoff);
  bf16x8 a2 = *(const bf16x8*)(A1 + aoff);
  bf16x8 a3 = *(const bf16x8*)(A2 + aoff);
  bf16x8 b1 = *(const bf16x8*)(B0 + boff);
  bf16x8 b2 = *(const bf16x8*)(B1 + boff);
  bf16x8 b3 = *(const bf16x8*)(B2 + boff);
  floatx16 c = *acc;
  c = __builtin_amdgcn_mfma_f32_32x32x16_bf16(a1,b1,c,0,0,0);
  c = __builtin_amdgcn_mfma_f32_32x32x16_bf16(a1,b2,c,0,0,0);
  c = __builtin_amdgcn_mfma_f32_32x32x16_bf16(a2,b1,c,0,0,0);
  c = __builtin_amdgcn_mfma_f32_32x32x16_bf16(a1,b3,c,0,0,0);
  c = __builtin_amdgcn_mfma_f32_32x32x16_bf16(a3,b1,c,0,0,0);
  c = __builtin_amdgcn_mfma_f32_32x32x16_bf16(a2,b2,c,0,0,0);
  *acc = c;
}

// ---- generic 64x128 MFMA GEMM core (bf16x6 fp32-faithful), batched loads + reg prefetch ----
// A0 may point to global or LDS (generic pointer).
__device__ __forceinline__ void g_gemm(const float* A0, int ldA,
                                       const float* __restrict__ W0, int ldW, int K,
                                       __bf16* pb, floatx16* oA, floatx16* oB){
  __bf16 *As0 = pb, *As1 = pb+2560, *As2 = pb+5120;
  __bf16 *Bs0 = pb+7680, *Bs1 = pb+12800, *Bs2 = pb+17920;
  int tid = threadIdx.x;
  int sar = tid >> 2, sako = (tid & 3)*8;
  int bn = tid & 127, bk = (tid >> 7)*16;
  int wv_ = tid >> 6, L = tid & 63, m = L & 31, half = L >> 5;
  int rA = 32*(wv_ & 1) + m, rB0 = (wv_ >> 1)*32 + m, rB1 = rB0 + 64;
  const float* arow = A0 + (size_t)sar*ldA;
  floatx16 accA, accB;
  #pragma unroll
  for (int i = 0; i < 16; i++){ accA[i] = 0.f; accB[i] = 0.f; }
  float ra[8], wv[16];
  {
    float4 v0 = *(const float4*)(arow + sako);
    float4 v1 = *(const float4*)(arow + sako + 4);
    ra[0]=v0.x; ra[1]=v0.y; ra[2]=v0.z; ra[3]=v0.w; ra[4]=v1.x; ra[5]=v1.y; ra[6]=v1.z; ra[7]=v1.w;
    #pragma unroll
    for (int j = 0; j < 16; j++) wv[j] = W0[(size_t)(bk + j)*ldW + bn];
  }
  for (int k0 = 0; k0 < K; k0 += 32){
    split_store8(ra, As0, As1, As2, SW(sar, sako));
    split_store8(wv,     Bs0, Bs1, Bs2, SW(bn, bk));
    split_store8(wv + 8, Bs0, Bs1, Bs2, SW(bn, bk + 8));
    __syncthreads();
    int k1 = k0 + 32;
    float ra2[8], wv2[16];
    if (k1 < K){
      float4 v0 = *(const float4*)(arow + k1 + sako);
      float4 v1 = *(const float4*)(arow + k1 + sako + 4);
      ra2[0]=v0.x; ra2[1]=v0.y; ra2[2]=v0.z; ra2[3]=v0.w; ra2[4]=v1.x; ra2[5]=v1.y; ra2[6]=v1.z; ra2[7]=v1.w;
      #pragma unroll
      for (int j = 0; j < 16; j++) wv2[j] = W0[(size_t)(k1 + bk + j)*ldW + bn];
    }
    #pragma unroll
    for (int kg = 0; kg < 2; kg++){
      int ko = kg*16 + half*8;
      mfma6(As0,As1,As2, Bs0,Bs1,Bs2, SW(rA,ko), SW(rB0,ko), &accA);
      mfma6(As0,As1,As2, Bs0,Bs1,Bs2, SW(rA,ko), SW(rB1,ko), &accB);
    }
    __syncthreads();
    if (k1 < K){
      #pragma unroll
      for (int j = 0; j < 8; j++) ra[j] = ra2[j];
      #pragma unroll
      for (int j = 0; j < 16; j++) wv[j] = wv2[j];
    }
  }
  *oA = accA; *oB = accB;
}

// ---- W1 GEMM core reading PRE-FOLDED W1f (K=384), h=[a,q,a*q] synthesized ----
__device__ __forceinline__ void g_gemm_h(const float* __restrict__ arow, const float* __restrict__ qrow,
                                         const float* __restrict__ W1fz, int colbase,
                                         __bf16* pb, floatx16* oA, floatx16* oB){
  __bf16 *As0 = pb, *As1 = pb+2560, *As2 = pb+5120;
  __bf16 *Bs0 = pb+7680, *Bs1 = pb+12800, *Bs2 = pb+17920;
  int tid = threadIdx.x;
  int sar = tid >> 2, sako = (tid & 3)*8;
  int bn = tid & 127, bk = (tid >> 7)*16;
  int col = colbase + bn;
  int wv_ = tid >> 6, L = tid & 63, m = L & 31, half = L >> 5;
  int rA = 32*(wv_ & 1) + m, rB0 = (wv_ >> 1)*32 + m, rB1 = rB0 + 64;
  auto loadA = [&](int k0, float* r){
    int seg = k0 >> 7, kl = (k0 & 127) + sako;
    if (seg == 0){
      float4 a0 = *(const float4*)(arow + kl), a1 = *(const float4*)(arow + kl + 4);
      r[0]=a0.x; r[1]=a0.y; r[2]=a0.z; r[3]=a0.w; r[4]=a1.x; r[5]=a1.y; r[6]=a1.z; r[7]=a1.w;
    } else if (seg == 1){
      float4 q0 = *(const float4*)(qrow + kl), q1 = *(const float4*)(qrow + kl + 4);
      r[0]=q0.x; r[1]=q0.y; r[2]=q0.z; r[3]=q0.w; r[4]=q1.x; r[5]=q1.y; r[6]=q1.z; r[7]=q1.w;
    } else {
      float4 a0 = *(const float4*)(arow + kl), a1 = *(const float4*)(arow + kl + 4);
      float4 q0 = *(const float4*)(qrow + kl), q1 = *(const float4*)(qrow + kl + 4);
      r[0]=a0.x*q0.x; r[1]=a0.y*q0.y; r[2]=a0.z*q0.z; r[3]=a0.w*q0.w;
      r[4]=a1.x*q1.x; r[5]=a1.y*q1.y; r[6]=a1.z*q1.z; r[7]=a1.w*q1.w;
    }
  };
  auto loadB = [&](int k0, float* r){
    #pragma unroll
    for (int j = 0; j < 16; j++) r[j] = W1fz[(size_t)(k0 + bk + j)*256 + col];
  };
  floatx16 accA, accB;
  #pragma unroll
  for (int i = 0; i < 16; i++){ accA[i] = 0.f; accB[i] = 0.f; }
  float ra[8], wv[16];
  loadA(0, ra); loadB(0, wv);
  for (int k0 = 0; k0 < 384; k0 += 32){
    split_store8(ra, As0, As1, As2, SW(sar, sako));
    split_store8(wv,     Bs0, Bs1, Bs2, SW(bn, bk));
    split_store8(wv + 8, Bs0, Bs1, Bs2, SW(bn, bk + 8));
    __syncthreads();
    int k1 = k0 + 32;
    float ra2[8], wv2[16];
    if (k1 < 384){ loadA(k1, ra2); loadB(k1, wv2); }
    #pragma unroll
    for (int kg = 0; kg < 2; kg++){
      int ko = kg*16 + half*8;
      mfma6(As0,As1,As2, Bs0,Bs1,Bs2, SW(rA,ko), SW(rB0,ko), &accA);
      mfma6(As0,As1,As2, Bs0,Bs1,Bs2, SW(rA,ko), SW(rB1,ko), &accB);
    }
    __syncthreads();
    if (k1 < 384){
      #pragma unroll
      for (int j = 0; j < 8; j++) ra[j] = ra2[j];
      #pragma unroll
      for (int j = 0; j < 16; j++) wv[j] = wv2[j];
    }
  }
  *oA = accA; *oB = accB;
}

__device__ __forceinline__ void c_write(floatx16 accA, floatx16 accB, float* C0, int ldC, int act){
  int tid = threadIdx.x, wv_ = tid >> 6, L = tid & 63, m = L & 31, half = L >> 5;
  int rB0 = (wv_ >> 1)*32 + m, rB1 = rB0 + 64;
  int row0 = 32*(wv_ & 1) + 4*half;
  #pragma unroll
  for (int reg = 0; reg < 16; reg++){
    int row = row0 + (reg & 3) + 8*(reg >> 2);
    float va = accA[reg], vb = accB[reg];
    if (act){ va = lrelu(va); vb = lrelu(vb); }
    C0[(size_t)row*ldC + rB0] = va;
    C0[(size_t)row*ldC + rB1] = vb;
  }
}

// ---- double hop (A^T twice), A in LDS; src either global rows or LDS 64x128 ----
__device__ __forceinline__ void hop2_run(const float* A, const float* VfullL,
                                         const float* srcG, float* dstG,
                                         float* Vt, float* Tt){
  int tid = threadIdx.x;
  int tc = (tid & 31)*2, tf = (tid >> 5)*4;
  for (int f0 = 0; f0 < 128; f0 += 32){
    if (!VfullL){
      for (int o = tid; o < 2048; o += 256){
        int r = o >> 5, f = o & 31;
        Vt[o] = srcG[r*128 + f0 + f];
      }
      __syncthreads();
    }
    float a00,a01,a02,a03,a10,a11,a12,a13;
    a00=a01=a02=a03=a10=a11=a12=a13=0.f;
    for (int r = 0; r < 64; r++){
      float x0 = A[r*64 + tc], x1 = A[r*64 + tc + 1];
      float4 v4 = VfullL ? *(const float4*)&VfullL[r*128 + f0 + tf]
                         : *(const float4*)&Vt[r*32 + tf];
      a00 += x0*v4.x; a01 += x0*v4.y; a02 += x0*v4.z; a03 += x0*v4.w;
      a10 += x1*v4.x; a11 += x1*v4.y; a12 += x1*v4.z; a13 += x1*v4.w;
    }
    *(float4*)&Tt[tc*32 + tf]     = make_float4(a00,a01,a02,a03);
    *(float4*)&Tt[(tc+1)*32 + tf] = make_float4(a10,a11,a12,a13);
    __syncthreads();
    a00=a01=a02=a03=a10=a11=a12=a13=0.f;
    for (int r = 0; r < 64; r++){
      float x0 = A[r*64 + tc], x1 = A[r*64 + tc + 1];
      float4 v4 = *(const float4*)&Tt[r*32 + tf];
      a00 += x0*v4.x; a01 += x0*v4.y; a02 += x0*v4.z; a03 += x0*v4.w;
      a10 += x1*v4.x; a11 += x1*v4.y; a12 += x1*v4.z; a13 += x1*v4.w;
    }
    *(float4*)(dstG + tc*128 + f0 + tf)     = make_float4(a00,a01,a02,a03);
    *(float4*)(dstG + (tc+1)*128 + f0 + tf) = make_float4(a10,a11,a12,a13);
    __syncthreads();
  }
}

// ===== K1: build A/M + hop2(x) (blk<64) || Wk pair-f GEMM (64..191) || W1 fold (192..255) =====
__global__ __launch_bounds__(256) void k_p0(const int* __restrict__ ei, const float* __restrict__ ew,
                                            const float* __restrict__ x, const float* __restrict__ Wk,
                                            const float* __restrict__ W1,
                                            float* A_g, float* M_g, float* xq, float* a_buf, float* W1f){
  __shared__ __align__(16) char POOL[57856];
  float* pf = (float*)POOL;
  __bf16* pb = (__bf16*)POOL;
  int blk = blockIdx.x, tid = threadIdx.x;
  if (blk < 64){
    int b = blk;
    float* Ws = pf; float* Mc = pf + 4096; float* dv = pf + 8192;
    for (int i = tid; i < 4096; i += 256){ Ws[i] = 0.f; Mc[i] = 0.f; }
    __syncthreads();
    const int* r0 = ei + b*2048;
    const int* c0 = ei + 64*2048 + b*2048;
    const float* w0 = ew + b*2048;
    int base = b*64;
    for (int e = tid; e < 2048; e += 256){
      int r = r0[e] - base, c = c0[e] - base;
      atomicAdd(&Ws[r*64 + c], w0[e]);
      atomicAdd(&Mc[r*64 + c], 1.f);
    }
    if (tid < 64){ atomicAdd(&Ws[tid*65], 1.f); atomicAdd(&Mc[tid*65], 1.f); }
    __syncthreads();
    if (tid < 64){
      float d = 0.f;
      for (int r = 0; r < 64; r++) d += Ws[r*64 + tid];
      dv[tid] = d > 0.f ? rsqrtf(fmaxf(d, 1e-12f)) : 0.f;
    }
    __syncthreads();
    for (int i = tid; i < 4096; i += 256){
      int r = i >> 6, c = i & 63;
      float a = dv[r]*Ws[i]*dv[c];
      Ws[i] = a;
      A_g[b*4096 + i] = a;
      M_g[b*4096 + i] = Mc[i];
    }
    __syncthreads();
    hop2_run(Ws, nullptr, x + (size_t)b*8192, xq + (size_t)b*8192, pf + 8256, pf + 10304);
  } else if (blk < 192){
    int idx = blk - 64, z = idx >> 6, b = idx & 63;
    floatx16 cA, cB;
    g_gemm(x + (size_t)b*8192, 128, Wk + (size_t)z*16384, 128, 128, pb, &cA, &cB);
    c_write(cA, cB, a_buf + (size_t)z*524288 + (size_t)b*8192, 128, 0);
  } else {
    // fold W1 (all 4 heads) -> W1f[head][384][256]
    int idx0 = (blk - 192)*6144;
    for (int i = tid; i < 6144; i += 256){
      int g = idx0 + i;
      int zz = g / 98304;
      int r = g - zz*98304;
      int kr = r >> 8, c = r & 255;
      const float* Wz = W1 + (size_t)zz*131072;
      float v;
      if (kr < 128)       v = Wz[kr*256 + c] + Wz[(kr + 256)*256 + c];
      else if (kr < 256)  v = Wz[kr*256 + c] - Wz[(kr + 128)*256 + c];
      else                v = Wz[(kr + 128)*256 + c];
      W1f[g] = v;
    }
  }
}

// ===== K2: W1 fold GEMM (256 blocks: b,z,nh) =====
__global__ __launch_bounds__(256) void k_h1(const float* __restrict__ a_buf, const float* __restrict__ q0,
                                            const float* __restrict__ tgt, const float* __restrict__ W1fp,
                                            float* h1){
  __shared__ __align__(16) char POOL[46080];
  __bf16* pb = (__bf16*)POOL;
  int blk = blockIdx.x, tid = threadIdx.x;
  int b = blk >> 2, z = (blk >> 1) & 1, nh = blk & 1;
  int sar = tid >> 2;
  const float* arow = a_buf + (size_t)z*524288 + ((size_t)b*64 + sar)*128;
  const float* qrow = z ? (tgt + (size_t)b*128) : (q0 + ((size_t)b*64 + sar)*128);
  floatx16 cA, cB;
  g_gemm_h(arow, qrow, W1fp + (size_t)z*98304, nh*128, pb, &cA, &cB);
  c_write(cA, cB, h1 + (size_t)z*1048576 + (size_t)b*64*256 + nh*128, 256, 1);
}

// ===== K3 (fused, 64 blocks): W2f(z0,z1)+W3+softmax -> edge+S+agg -> lin+x_c -> hop2 -> Wk-g =====
__global__ __launch_bounds__(256) void k_fuse1(const float* __restrict__ h1, const float* __restrict__ W2,
                                               const float* __restrict__ W3, const float* __restrict__ M_g,
                                               const float* __restrict__ x, const float* __restrict__ linW,
                                               const float* __restrict__ A_g, const float* __restrict__ Wkg,
                                               float* S_g, float* xq2, float* a_buf){
  __shared__ __align__(16) char POOL[129024];
  float* pf  = (float*)POOL;
  __bf16* pb = (__bf16*)POOL;
  float* lgp = (float*)(POOL + 46080);   // 128
  float* f1s = (float*)(POOL + 46592);   // 64
  float* f2s = (float*)(POOL + 46848);   // 64
  float* Mc  = (float*)(POOL + 47104);   // 4096
  float* xb  = (float*)(POOL + 63488);   // 8192 (later: xcV)
  float* aggL= (float*)(POOL + 96256);   // 8192
  int b = blockIdx.x, tid = threadIdx.x;
  int wv_ = tid >> 6, L = tid & 63, m = L & 31, half = L >> 5;
  int rB0 = (wv_ >> 1)*32 + m, rB1 = rB0 + 64;
  // ---- Phase A: W2 + W3 + per-batch softmax for z=0,1 ----
  for (int z = 0; z < 2; z++){
    floatx16 cA, cB;
    g_gemm(h1 + (size_t)z*1048576 + (size_t)b*16384, 256, W2 + (size_t)z*32768, 128, 256, pb, &cA, &cB);
    const float* W3z = W3 + z*128;
    float wA = W3z[rB0], wB = W3z[rB1];
    float c[16];
    #pragma unroll
    for (int reg = 0; reg < 16; reg++) c[reg] = lrelu(cA[reg])*wA + lrelu(cB[reg])*wB;
    #pragma unroll
    for (int off = 1; off < 32; off <<= 1)
      #pragma unroll
      for (int reg = 0; reg < 16; reg++) c[reg] += __shfl_xor(c[reg], off);
    if (m == 0){
      #pragma unroll
      for (int reg = 0; reg < 16; reg++) lgp[wv_*32 + half*16 + reg] = c[reg];
    }
    __syncthreads();
    if (tid < 64){
      int row = tid, wva = row >> 5, rem = row & 31;
      int hf = (rem >> 2) & 1, rg = (rem & 3) + 4*(rem >> 3);
      float l = lrelu(lgp[wva*32 + hf*16 + rg] + lgp[(wva + 2)*32 + hf*16 + rg]);
      float mx = l;
      #pragma unroll
      for (int off = 32; off; off >>= 1) mx = fmaxf(mx, __shfl_xor(mx, off));
      float e = expf(l - mx);
      float s = e;
      #pragma unroll
      for (int off = 32; off; off >>= 1) s += __shfl_xor(s, off);
      (z ? f2s : f1s)[row] = e/s;
    }
    __syncthreads();
  }
  // ---- Phase B: edge softmax + S + agg (agg stays in LDS) ----
  for (int i = tid; i < 4096; i += 256) Mc[i] = M_g[b*4096 + i];
  for (int i = tid*4; i < 8192; i += 1024)
    *(float4*)&xb[i] = *(const float4*)(x + (size_t)b*8192 + i);
  __syncthreads();
  {
    int c = tid >> 2, sub = tid & 3;
    float mm = -1e30f;
    for (int r = sub; r < 64; r += 4)
      if (Mc[r*64 + c] > 0.f) mm = fmaxf(mm, lrelu(f1s[c] + f2s[r]));
    mm = fmaxf(mm, __shfl_xor(mm, 1));
    mm = fmaxf(mm, __shfl_xor(mm, 2));
    float s = 0.f;
    for (int r = sub; r < 64; r += 4){
      float mc = Mc[r*64 + c];
      if (mc > 0.f) s += mc*expf(lrelu(f1s[c] + f2s[r]) - mm);
    }
    s += __shfl_xor(s, 1);
    s += __shfl_xor(s, 2);
    for (int r = sub; r < 64; r += 4){
      float mc = Mc[r*64 + c];
      float v = 0.f;
      if (mc > 0.f) v = mc*expf(lrelu(f1s[c] + f2s[r]) - mm)/s;
      Mc[r*64 + c] = v;
    }
  }
  __syncthreads();
  for (int i = tid; i < 4096; i += 256) S_g[b*4096 + i] = Mc[i];
  {
    int tc = (tid & 15)*4, tf = (tid >> 4)*8;
    float acc[4][8];
    #pragma unroll
    for (int i = 0; i < 4; i++)
      #pragma unroll
      for (int j = 0; j < 8; j++) acc[i][j] = 0.f;
    for (int r = 0; r < 64; r++){
      float4 e4 = *(const float4*)&Mc[r*64 + tc];
      float4 x0 = *(const float4*)&xb[r*128 + tf];
      float4 x1 = *(const float4*)&xb[r*128 + tf + 4];
      float e_[4] = {e4.x,e4.y,e4.z,e4.w};
      float x_[8] = {x0.x,x0.y,x0.z,x0.w,x1.x,x1.y,x1.z,x1.w};
      #pragma unroll
      for (int ci = 0; ci < 4; ci++)
        #pragma unroll
        for (int fj = 0; fj < 8; fj++) acc[ci][fj] += e_[ci]*x_[fj];
    }
    #pragma unroll
    for (int ci = 0; ci < 4; ci++){
      *(float4*)&aggL[(tc+ci)*128 + tf]     = make_float4(acc[ci][0],acc[ci][1],acc[ci][2],acc[ci][3]);
      *(float4*)&aggL[(tc+ci)*128 + tf + 4] = make_float4(acc[ci][4],acc[ci][5],acc[ci][6],acc[ci][7]);
    }
  }
  __syncthreads();
  // ---- Phase C: lin GEMMs (A from LDS aggL) ----
  floatx16 h0A, h0B, h1A, h1B2;
  g_gemm(aggL, 128, linW, 128, 128, pb, &h0A, &h0B);
  g_gemm(aggL, 128, linW + 16384, 128, 128, pb, &h1A, &h1B2);
  // ---- Phase D: x_c -> xcV (reuses xb region; xb dead) ----
  float* xcV = xb;
  {
    int row0 = 32*(wv_ & 1) + 4*half;
    #pragma unroll
    for (int reg = 0; reg < 16; reg++){
      int row = row0 + (reg & 3) + 8*(reg >> 2);
      float xv0 = x[((size_t)b*64 + row)*128 + rB0];
      float v0 = 0.5f*(lrelu(xv0 + h0A[reg]) + lrelu(xv0 + h1A[reg]));
      xcV[row*128 + rB0] = v0;
      float xv1 = x[((size_t)b*64 + row)*128 + rB1];
      float v1 = 0.5f*(lrelu(xv1 + h0B[reg]) + lrelu(xv1 + h1B2[reg]));
      xcV[row*128 + rB1] = v1;
    }
  }
  // ---- Phase E: hop2(x_c) -> xq2 (Ab/Tt in dead staging region) ----
  float* Ab = pf;                       // 4096 floats at POOL+0
  float* Tt = (float*)(POOL + 16384);   // 2048 floats
  for (int i = tid*4; i < 4096; i += 1024)
    *(float4*)&Ab[i] = *(const float4*)(A_g + b*4096 + i);
  __syncthreads();
  hop2_run(Ab, xcV, nullptr, xq2 + (size_t)b*8192, Tt, Tt);
  // ---- Phase F: Wk pair-g GEMMs (A from LDS xcV) ----
  for (int z = 0; z < 2; z++){
    floatx16 cA, cB;
    g_gemm(xcV, 128, Wkg + (size_t)z*16384, 128, 128, pb, &cA, &cB);
    c_write(cA, cB, a_buf + (size_t)z*524288 + (size_t)b*8192, 128, 0);
  }
}

// ===== K5 (fused, 64 blocks): W2g(z0,z1)+W3+softmax -> bitonic top-52 + x_out -> C2 =====
__global__ __launch_bounds__(256) void k_fuse2(const float* __restrict__ h1, const float* __restrict__ W2g,
                                               const float* __restrict__ W3g, const float* __restrict__ x,
                                               const float* __restrict__ A_g, const float* __restrict__ S_g,
                                               float* C2g, float* outX, float* outB, float* outP){
  __shared__ __align__(16) char POOL[47616];
  float* pf  = (float*)POOL;
  __bf16* pb = (__bf16*)POOL;
  float* lgp = (float*)(POOL + 46080);
  float* g1s = (float*)(POOL + 46592);
  float* g2s = (float*)(POOL + 46848);
  int*   pi  = (int*)(POOL + 47104);
  float* pv  = (float*)(POOL + 47360);
  int b = blockIdx.x, tid = threadIdx.x;
  int wv_ = tid >> 6, L = tid & 63, m = L & 31, half = L >> 5;
  int rB0 = (wv_ >> 1)*32 + m, rB1 = rB0 + 64;
  // ---- Phase A: W2 + W3 + per-batch softmax for z=0,1 ----
  for (int z = 0; z < 2; z++){
    floatx16 cA, cB;
    g_gemm(h1 + (size_t)z*1048576 + (size_t)b*16384, 256, W2g + (size_t)z*32768, 128, 256, pb, &cA, &cB);
    const float* W3z = W3g + z*128;
    float wA = W3z[rB0], wB = W3z[rB1];
    float c[16];
    #pragma unroll
    for (int reg = 0; reg < 16; reg++) c[reg] = lrelu(cA[reg])*wA + lrelu(cB[reg])*wB;
    #pragma unroll
    for (int off = 1; off < 32; off <<= 1)
      #pragma unroll
      for (int reg = 0; reg < 16; reg++) c[reg] += __shfl_xor(c[reg], off);
    if (m == 0){
      #pragma unroll
      for (int reg = 0; reg < 16; reg++) lgp[wv_*32 + half*16 + reg] = c[reg];
    }
    __syncthreads();
    if (tid < 64){
      int row = tid, wva = row >> 5, rem = row & 31;
      int hf = (rem >> 2) & 1, rg = (rem & 3) + 4*(rem >> 3);
      float l = lrelu(lgp[wva*32 + hf*16 + rg] + lgp[(wva + 2)*32 + hf*16 + rg]);
      float mx = l;
      #pragma unroll
      for (int off = 32; off; off >>= 1) mx = fmaxf(mx, __shfl_xor(mx, off));
      float e = expf(l - mx);
      float s = e;
      #pragma unroll
      for (int off = 32; off; off >>= 1) s += __shfl_xor(s, off);
      (z ? g2s : g1s)[row] = e/s;
    }
    __syncthreads();
  }
  // ---- Phase B: cluster softmax + bitonic top-52 ----
  if (tid < 64){
    int lane = tid;
    float l = g1s[lane] + g2s[lane];
    float mx = l;
    #pragma unroll
    for (int off = 32; off; off >>= 1) mx = fmaxf(mx, __shfl_xor(mx, off));
    float e = expf(l - mx);
    float sm = e;
    #pragma unroll
    for (int off = 32; off; off >>= 1) sm += __shfl_xor(sm, off);
    float v = e/sm;
    int idx = lane;
    #pragma unroll
    for (int k = 2; k <= 64; k <<= 1){
      #pragma unroll
      for (int j = k >> 1; j > 0; j >>= 1){
        float ov = __shfl_xor(v, j);
        int   oi = __shfl_xor(idx, j);
        bool ascBlock = (lane & k) == 0;
        bool iAmLow   = (lane & j) == 0;
        bool otherPrec = (ov > v) || (ov == v && oi < idx);
        bool take = (ascBlock == iAmLow) ? otherPrec : !otherPrec;
        if (take){ v = ov; idx = oi; }
      }
    }
    pi[lane] = idx; pv[lane] = v;
    if (lane < KK){
      outB[b*KK + lane] = (float)b;
      outP[b*KK + lane] = (float)(b*64 + idx);
    }
  }
  __syncthreads();
  // ---- Phase C: x_out gather ----
  for (int o = tid*4; o < KK*128; o += 1024){
    int j = o >> 7, f = o & 127;
    float4 xv = *(const float4*)(x + ((size_t)b*64 + pi[j])*128 + f);
    float sv = pv[j];
    *(float4*)(outX + (size_t)b*KK*128 + o) = make_float4(xv.x*sv, xv.y*sv, xv.z*sv, xv.w*sv);
  }
  // ---- Phase D: C2 = S_p^T (A S_p), diag=1 (At/Sp/Tq in dead staging region) ----
  float* At = pf;                        // 64*68
  float* Sp = (float*)(POOL + 17408);    // 64*56
  float* Tq = (float*)(POOL + 31744);    // 64*56
  for (int idx = tid; idx < 4096; idx += 256){
    int i = idx >> 6, k = idx & 63;
    At[k*68 + i] = A_g[b*4096 + idx];
  }
  for (int idx = tid; idx < 4096; idx += 256){
    int k = idx >> 6, t = idx & 63;
    if (t < 56) Sp[k*56 + t] = (t < KK) ? S_g[b*4096 + k*64 + pi[t]] : 0.f;
  }
  __syncthreads();
  if (tid < 224){
    int i0 = (tid/14)*4, t0 = (tid % 14)*4;
    float acc[4][4];
    #pragma unroll
    for (int a = 0; a < 4; a++)
      #pragma unroll
      for (int c = 0; c < 4; c++) acc[a][c] = 0.f;
    for (int k = 0; k < 64; k++){
      float4 a4 = *(const float4*)&At[k*68 + i0];
      float4 s4 = *(const float4*)&Sp[k*56 + t0];
      float a_[4] = {a4.x,a4.y,a4.z,a4.w};
      float s_[4] = {s4.x,s4.y,s4.z,s4.w};
      #pragma unroll
      for (int ii = 0; ii < 4; ii++)
        #pragma unroll
        for (int tt = 0; tt < 4; tt++) acc[ii][tt] += a_[ii]*s_[tt];
    }
    #pragma unroll
    for (int ii = 0; ii < 4; ii++)
      *(float4*)&Tq[(i0+ii)*56 + t0] = make_float4(acc[ii][0],acc[ii][1],acc[ii][2],acc[ii][3]);
  }
  __syncthreads();
  if (tid < 169){
    int a0 = (tid/13)*4, t0 = (tid % 13)*4;
    float acc[4][4];
    #pragma unroll
    for (int a = 0; a < 4; a++)
      #pragma unroll
      for (int c = 0; c < 4; c++) acc[a][c] = 0.f;
    for (int i = 0; i < 64; i++){
      float4 s4 = *(const float4*)&Sp[i*56 + a0];
      float4 t4 = *(const float4*)&Tq[i*56 + t0];
      float s_[4] = {s4.x,s4.y,s4.z,s4.w};
      float t_[4] = {t4.x,t4.y,t4.z,t4.w};
      #pragma unroll
      for (int aa = 0; aa < 4; aa++)
        #pragma unroll
        for (int tt = 0; tt < 4; tt++) acc[aa][tt] += s_[aa]*t_[tt];
    }
    #pragma unroll
    for (int aa = 0; aa < 4; aa++)
      #pragma unroll
      for (int tt = 0; tt < 4; tt++){
        int a = a0 + aa, t = t0 + tt;
        C2g[b*(KK*KK) + a*KK + t] = (a == t) ? 1.f : acc[aa][tt];
      }
  }
}

// ===== K6: bulk A2 write (10816 blocks, 1 float4/thread) =====
__global__ __launch_bounds__(256) void k_A2w(const float* __restrict__ C2g, float* __restrict__ outA2){
  int g = blockIdx.x*256 + threadIdx.x;      // 0 .. 2768895 (float4 index)
  int row = g/832, c4 = g - row*832;         // 832 float4 per row
  int b = row/KK, al = row - b*KK;
  int rel = c4 - b*13;
  float4 val;
  if (rel >= 0 && rel < 13){
    val = *(const float4*)(C2g + (size_t)b*(KK*KK) + al*KK + rel*4);
  } else {
    val = make_float4(0.f, 0.f, 0.f, 0.f);
  }
  *(float4*)(outA2 + (size_t)g*4) = val;
}

extern "C" void kernel_launch(void* const* d_in, const int* in_sizes, int n_in,
                              void* d_out, int out_size, void* d_ws, size_t ws_size,
                              hipStream_t stream){
  const float* x    = (const float*)d_in[0];
  const int*   ei   = (const int*)d_in[1];
  const float* ew   = (const float*)d_in[2];
  const float* tgt  = (const float*)d_in[3];
  const float* Wk   = (const float*)d_in[5];
  const float* W1   = (const float*)d_in[6];
  const float* W2   = (const float*)d_in[7];
  const float* W3   = (const float*)d_in[8];
  const float* linW = (const float*)d_in[9];
  float* out = (float*)d_out;

  float* wf   = (float*)d_ws;
  float* A_g  = wf;
  float* M_g  = wf + 262144;
  float* S_g  = wf + 524288;
  float* xq   = wf + 786432;
  float* xq2  = wf + 1310720;
  float* a_buf= wf + 2883584;   // 2 x 524288
  float* h1   = wf + 3932160;   // 2 x 1048576
  float* W1f  = wf + 6045696;   // 4 x 98304 = 393216
  float* C2g  = wf + 6438912;   // 64 x 2704 = 173056

  float* outX  = out;
  float* outA2 = out + 425984;
  float* outB  = out + 425984 + 11075584;
  float* outP  = outB + NKOUT;

  // pair f (+ W1 pre-fold in spare blocks)
  k_p0<<<dim3(256), dim3(256), 0, stream>>>(ei, ew, x, Wk, W1, A_g, M_g, xq, a_buf, W1f);
  k_h1<<<dim3(256), dim3(256), 0, stream>>>(a_buf, xq, tgt, W1f, h1);
  // fused: W2f + softmax -> edge + S + agg -> lin + x_c -> hop2 -> Wk-g
  k_fuse1<<<dim3(64), dim3(256), 0, stream>>>(h1, W2, W3, M_g, x, linW, A_g, Wk + 2*16384,
                                              S_g, xq2, a_buf);
  // pair g W1
  k_h1<<<dim3(256), dim3(256), 0, stream>>>(a_buf, xq2, tgt, W1f + 2*98304, h1);
  // fused: W2g + softmax -> pool (bitonic) + x_out -> C2
  k_fuse2<<<dim3(64), dim3(256), 0, stream>>>(h1, W2 + 2*32768, W3 + 2*128, x, A_g, S_g,
                                              C2g, outX, outB, outP);
  // bulk A2 write
  k_A2w<<<dim3(10816), dim3(256), 0, stream>>>(C2g, outA2);
}

// Round 11
// 257.549 us; speedup vs baseline: 1.1022x; 1.1022x over previous
//
#include <hip/hip_runtime.h>

// B=64 batches, n=64 nodes/batch, H=128, epg=2048 edges/batch
#define KK 52
#define NKOUT 3328
#define NEG 0.01f

typedef __attribute__((ext_vector_type(8))) __bf16 bf16x8;
typedef __attribute__((ext_vector_type(16))) float floatx16;

__device__ __forceinline__ float lrelu(float v){ return v > 0.f ? v : NEG*v; }

// LDS layout for MFMA chunks: row pitch 40 bf16 (80B); XOR swizzle on 16B chunks
#define SW(r, ko) ((r)*40 + ((ko) ^ ((((r)>>3)&3) << 3)))

__device__ __forceinline__ void split_store8(const float* vv, __bf16* P0, __bf16* P1, __bf16* P2, int addr){
  bf16x8 p1, p2, p3;
  #pragma unroll
  for (int j = 0; j < 8; j++){
    __bf16 b1 = (__bf16)vv[j];
    float r1 = vv[j] - (float)b1;
    __bf16 b2 = (__bf16)r1;
    float r2 = r1 - (float)b2;
    p1[j] = b1; p2[j] = b2; p3[j] = (__bf16)r2;
  }
  *(bf16x8*)(P0 + addr) = p1;
  *(bf16x8*)(P1 + addr) = p2;
  *(bf16x8*)(P2 + addr) = p3;
}

__device__ __forceinline__ void mfma6(const __bf16* A0, const __bf16* A1, const __bf16* A2,
                                      const __bf16* B0, const __bf16* B1, const __bf16* B2,
                                      int aoff, int boff, floatx16* acc){
  bf16x8 a1 = *(const bf16x8*)(A0 + aoff);
  bf16x8 a2 = *(const bf16x8*)(A1 + aoff);
  bf16x8 a3 = *(const bf16x8*)(A2 + aoff);
  bf16x8 b1 = *(const bf16x8*)(B0 + boff);
  bf16x8 b2 = *(const bf16x8*)(B1 + boff);
  bf16x8 b3 = *(const bf16x8*)(B2 + boff);
  floatx16 c = *acc;
  c = __builtin_amdgcn_mfma_f32_32x32x16_bf16(a1,b1,c,0,0,0);
  c = __builtin_amdgcn_mfma_f32_32x32x16_bf16(a1,b2,c,0,0,0);
  c = __builtin_amdgcn_mfma_f32_32x32x16_bf16(a2,b1,c,0,0,0);
  c = __builtin_amdgcn_mfma_f32_32x32x16_bf16(a1,b3,c,0,0,0);
  c = __builtin_amdgcn_mfma_f32_32x32x16_bf16(a3,b1,c,0,0,0);
  c = __builtin_amdgcn_mfma_f32_32x32x16_bf16(a2,b2,c,0,0,0);
  *acc = c;
}

// ---- generic 64x128 MFMA GEMM core (bf16x6 fp32-faithful), batched loads + reg prefetch ----
__device__ __forceinline__ void g_gemm(const float* __restrict__ A0, int ldA,
                                       const float* __restrict__ W0, int ldW, int K,
                                       __bf16* pb, floatx16* oA, floatx16* oB){
  __bf16 *As0 = pb, *As1 = pb+2560, *As2 = pb+5120;
  __bf16 *Bs0 = pb+7680, *Bs1 = pb+12800, *Bs2 = pb+17920;
  int tid = threadIdx.x;
  int sar = tid >> 2, sako = (tid & 3)*8;
  int bn = tid & 127, bk = (tid >> 7)*16;
  int wv_ = tid >> 6, L = tid & 63, m = L & 31, half = L >> 5;
  int rA = 32*(wv_ & 1) + m, rB0 = (wv_ >> 1)*32 + m, rB1 = rB0 + 64;
  const float* arow = A0 + (size_t)sar*ldA;
  floatx16 accA, accB;
  #pragma unroll
  for (int i = 0; i < 16; i++){ accA[i] = 0.f; accB[i] = 0.f; }
  float ra[8], wv[16];
  {
    float4 v0 = *(const float4*)(arow + sako);
    float4 v1 = *(const float4*)(arow + sako + 4);
    ra[0]=v0.x; ra[1]=v0.y; ra[2]=v0.z; ra[3]=v0.w; ra[4]=v1.x; ra[5]=v1.y; ra[6]=v1.z; ra[7]=v1.w;
    #pragma unroll
    for (int j = 0; j < 16; j++) wv[j] = W0[(size_t)(bk + j)*ldW + bn];
  }
  for (int k0 = 0; k0 < K; k0 += 32){
    split_store8(ra, As0, As1, As2, SW(sar, sako));
    split_store8(wv,     Bs0, Bs1, Bs2, SW(bn, bk));
    split_store8(wv + 8, Bs0, Bs1, Bs2, SW(bn, bk + 8));
    __syncthreads();
    int k1 = k0 + 32;
    float ra2[8], wv2[16];
    if (k1 < K){
      float4 v0 = *(const float4*)(arow + k1 + sako);
      float4 v1 = *(const float4*)(arow + k1 + sako + 4);
      ra2[0]=v0.x; ra2[1]=v0.y; ra2[2]=v0.z; ra2[3]=v0.w; ra2[4]=v1.x; ra2[5]=v1.y; ra2[6]=v1.z; ra2[7]=v1.w;
      #pragma unroll
      for (int j = 0; j < 16; j++) wv2[j] = W0[(size_t)(k1 + bk + j)*ldW + bn];
    }
    #pragma unroll
    for (int kg = 0; kg < 2; kg++){
      int ko = kg*16 + half*8;
      mfma6(As0,As1,As2, Bs0,Bs1,Bs2, SW(rA,ko), SW(rB0,ko), &accA);
      mfma6(As0,As1,As2, Bs0,Bs1,Bs2, SW(rA,ko), SW(rB1,ko), &accB);
    }
    __syncthreads();
    if (k1 < K){
      #pragma unroll
      for (int j = 0; j < 8; j++) ra[j] = ra2[j];
      #pragma unroll
      for (int j = 0; j < 16; j++) wv[j] = wv2[j];
    }
  }
  *oA = accA; *oB = accB;
}

// ---- 64x64-tile W1 GEMM core (K=384, pre-folded W1f, h=[a,q,a*q] synthesized) ----
// 4 waves, one 32x32 quadrant each; 2 blocks/CU at 512-block grid. Bit-identical per-output order.
__device__ __forceinline__ void g_gemm_h64(const float* __restrict__ arow, const float* __restrict__ qrow,
                                           const float* __restrict__ W1fz, int colbase,
                                           __bf16* pb, floatx16* oC){
  __bf16 *As0 = pb, *As1 = pb+2560, *As2 = pb+5120;
  __bf16 *Bs0 = pb+7680, *Bs1 = pb+10240, *Bs2 = pb+12800;
  int tid = threadIdx.x;
  int sar = tid >> 2, sako = (tid & 3)*8;
  int bn = tid & 63, bk = (tid >> 6)*8;
  int col = colbase + bn;
  int wv_ = tid >> 6, L = tid & 63, m = L & 31, half = L >> 5;
  int rA = 32*(wv_ & 1) + m, rB = 32*(wv_ >> 1) + m;
  auto loadA = [&](int k0, float* r){
    int seg = k0 >> 7, kl = (k0 & 127) + sako;
    if (seg == 0){
      float4 a0 = *(const float4*)(arow + kl), a1 = *(const float4*)(arow + kl + 4);
      r[0]=a0.x; r[1]=a0.y; r[2]=a0.z; r[3]=a0.w; r[4]=a1.x; r[5]=a1.y; r[6]=a1.z; r[7]=a1.w;
    } else if (seg == 1){
      float4 q0 = *(const float4*)(qrow + kl), q1 = *(const float4*)(qrow + kl + 4);
      r[0]=q0.x; r[1]=q0.y; r[2]=q0.z; r[3]=q0.w; r[4]=q1.x; r[5]=q1.y; r[6]=q1.z; r[7]=q1.w;
    } else {
      float4 a0 = *(const float4*)(arow + kl), a1 = *(const float4*)(arow + kl + 4);
      float4 q0 = *(const float4*)(qrow + kl), q1 = *(const float4*)(qrow + kl + 4);
      r[0]=a0.x*q0.x; r[1]=a0.y*q0.y; r[2]=a0.z*q0.z; r[3]=a0.w*q0.w;
      r[4]=a1.x*q1.x; r[5]=a1.y*q1.y; r[6]=a1.z*q1.z; r[7]=a1.w*q1.w;
    }
  };
  auto loadB = [&](int k0, float* r){
    #pragma unroll
    for (int j = 0; j < 8; j++) r[j] = W1fz[(size_t)(k0 + bk + j)*256 + col];
  };
  floatx16 acc;
  #pragma unroll
  for (int i = 0; i < 16; i++) acc[i] = 0.f;
  float ra[8], wv[8];
  loadA(0, ra); loadB(0, wv);
  for (int k0 = 0; k0 < 384; k0 += 32){
    split_store8(ra, As0, As1, As2, SW(sar, sako));
    split_store8(wv, Bs0, Bs1, Bs2, SW(bn, bk));
    __syncthreads();
    int k1 = k0 + 32;
    float ra2[8], wv2[8];
    if (k1 < 384){ loadA(k1, ra2); loadB(k1, wv2); }
    #pragma unroll
    for (int kg = 0; kg < 2; kg++){
      int ko = kg*16 + half*8;
      mfma6(As0,As1,As2, Bs0,Bs1,Bs2, SW(rA,ko), SW(rB,ko), &acc);
    }
    __syncthreads();
    if (k1 < 384){
      #pragma unroll
      for (int j = 0; j < 8; j++){ ra[j] = ra2[j]; wv[j] = wv2[j]; }
    }
  }
  *oC = acc;
}

__device__ __forceinline__ void c_write(floatx16 accA, floatx16 accB, float* C0, int ldC, int act){
  int tid = threadIdx.x, wv_ = tid >> 6, L = tid & 63, m = L & 31, half = L >> 5;
  int rB0 = (wv_ >> 1)*32 + m, rB1 = rB0 + 64;
  int row0 = 32*(wv_ & 1) + 4*half;
  #pragma unroll
  for (int reg = 0; reg < 16; reg++){
    int row = row0 + (reg & 3) + 8*(reg >> 2);
    float va = accA[reg], vb = accB[reg];
    if (act){ va = lrelu(va); vb = lrelu(vb); }
    C0[(size_t)row*ldC + rB0] = va;
    C0[(size_t)row*ldC + rB1] = vb;
  }
}

__device__ __forceinline__ void c_write64(floatx16 acc, float* C0, int ldC, int act){
  int tid = threadIdx.x, wv_ = tid >> 6, L = tid & 63, m = L & 31, half = L >> 5;
  int col = 32*(wv_ >> 1) + m;
  int row0 = 32*(wv_ & 1) + 4*half;
  #pragma unroll
  for (int reg = 0; reg < 16; reg++){
    int row = row0 + (reg & 3) + 8*(reg >> 2);
    float v = acc[reg];
    if (act) v = lrelu(v);
    C0[(size_t)row*ldC + col] = v;
  }
}

// ---- double hop (A^T twice), A in LDS; src either global rows or LDS 64x128 ----
__device__ __forceinline__ void hop2_run(const float* A, const float* VfullL,
                                         const float* srcG, float* dstG,
                                         float* Vt, float* Tt){
  int tid = threadIdx.x;
  int tc = (tid & 31)*2, tf = (tid >> 5)*4;
  for (int f0 = 0; f0 < 128; f0 += 32){
    if (!VfullL){
      for (int o = tid; o < 2048; o += 256){
        int r = o >> 5, f = o & 31;
        Vt[o] = srcG[r*128 + f0 + f];
      }
      __syncthreads();
    }
    float a00,a01,a02,a03,a10,a11,a12,a13;
    a00=a01=a02=a03=a10=a11=a12=a13=0.f;
    for (int r = 0; r < 64; r++){
      float x0 = A[r*64 + tc], x1 = A[r*64 + tc + 1];
      float4 v4 = VfullL ? *(const float4*)&VfullL[r*128 + f0 + tf]
                         : *(const float4*)&Vt[r*32 + tf];
      a00 += x0*v4.x; a01 += x0*v4.y; a02 += x0*v4.z; a03 += x0*v4.w;
      a10 += x1*v4.x; a11 += x1*v4.y; a12 += x1*v4.z; a13 += x1*v4.w;
    }
    *(float4*)&Tt[tc*32 + tf]     = make_float4(a00,a01,a02,a03);
    *(float4*)&Tt[(tc+1)*32 + tf] = make_float4(a10,a11,a12,a13);
    __syncthreads();
    a00=a01=a02=a03=a10=a11=a12=a13=0.f;
    for (int r = 0; r < 64; r++){
      float x0 = A[r*64 + tc], x1 = A[r*64 + tc + 1];
      float4 v4 = *(const float4*)&Tt[r*32 + tf];
      a00 += x0*v4.x; a01 += x0*v4.y; a02 += x0*v4.z; a03 += x0*v4.w;
      a10 += x1*v4.x; a11 += x1*v4.y; a12 += x1*v4.z; a13 += x1*v4.w;
    }
    *(float4*)(dstG + tc*128 + f0 + tf)     = make_float4(a00,a01,a02,a03);
    *(float4*)(dstG + (tc+1)*128 + f0 + tf) = make_float4(a10,a11,a12,a13);
    __syncthreads();
  }
}

// ===== K1: build A/M + hop2(x) (blk<64) || Wk pair-f GEMM (64..191) || W1 fold (192..255) =====
__global__ __launch_bounds__(256) void k_p0(const int* __restrict__ ei, const float* __restrict__ ew,
                                            const float* __restrict__ x, const float* __restrict__ Wk,
                                            const float* __restrict__ W1,
                                            float* A_g, float* M_g, float* xq, float* a_buf, float* W1f){
  __shared__ __align__(16) char POOL[57856];
  float* pf = (float*)POOL;
  __bf16* pb = (__bf16*)POOL;
  int blk = blockIdx.x, tid = threadIdx.x;
  if (blk < 64){
    int b = blk;
    float* Ws = pf; float* Mc = pf + 4096; float* dv = pf + 8192;
    for (int i = tid; i < 4096; i += 256){ Ws[i] = 0.f; Mc[i] = 0.f; }
    __syncthreads();
    const int* r0 = ei + b*2048;
    const int* c0 = ei + 64*2048 + b*2048;
    const float* w0 = ew + b*2048;
    int base = b*64;
    for (int e = tid; e < 2048; e += 256){
      int r = r0[e] - base, c = c0[e] - base;
      atomicAdd(&Ws[r*64 + c], w0[e]);
      atomicAdd(&Mc[r*64 + c], 1.f);
    }
    if (tid < 64){ atomicAdd(&Ws[tid*65], 1.f); atomicAdd(&Mc[tid*65], 1.f); }
    __syncthreads();
    if (tid < 64){
      float d = 0.f;
      for (int r = 0; r < 64; r++) d += Ws[r*64 + tid];
      dv[tid] = d > 0.f ? rsqrtf(fmaxf(d, 1e-12f)) : 0.f;
    }
    __syncthreads();
    for (int i = tid; i < 4096; i += 256){
      int r = i >> 6, c = i & 63;
      float a = dv[r]*Ws[i]*dv[c];
      Ws[i] = a;
      A_g[b*4096 + i] = a;
      M_g[b*4096 + i] = Mc[i];
    }
    __syncthreads();
    hop2_run(Ws, nullptr, x + (size_t)b*8192, xq + (size_t)b*8192, pf + 8256, pf + 10304);
  } else if (blk < 192){
    int idx = blk - 64, z = idx >> 6, b = idx & 63;
    floatx16 cA, cB;
    g_gemm(x + (size_t)b*8192, 128, Wk + (size_t)z*16384, 128, 128, pb, &cA, &cB);
    c_write(cA, cB, a_buf + (size_t)z*524288 + (size_t)b*8192, 128, 0);
  } else {
    // fold W1 (all 4 heads) -> W1f[head][384][256]
    int idx0 = (blk - 192)*6144;
    for (int i = tid; i < 6144; i += 256){
      int g = idx0 + i;
      int zz = g / 98304;
      int r = g - zz*98304;
      int kr = r >> 8, c = r & 255;
      const float* Wz = W1 + (size_t)zz*131072;
      float v;
      if (kr < 128)       v = Wz[kr*256 + c] + Wz[(kr + 256)*256 + c];
      else if (kr < 256)  v = Wz[kr*256 + c] - Wz[(kr + 128)*256 + c];
      else                v = Wz[(kr + 128)*256 + c];
      W1f[g] = v;
    }
  }
}

// ===== K2: W1 fold GEMM (512 blocks: b,z,nq) — 64x64 tiles, 2 blocks/CU =====
__global__ __launch_bounds__(256) void k_h1(const float* __restrict__ a_buf, const float* __restrict__ q0,
                                            const float* __restrict__ tgt, const float* __restrict__ W1fp,
                                            float* h1){
  __shared__ __align__(16) char POOL[30720];
  __bf16* pb = (__bf16*)POOL;
  int blk = blockIdx.x, tid = threadIdx.x;
  int b = blk >> 3, z = (blk >> 2) & 1, nq = blk & 3;
  int sar = tid >> 2;
  const float* arow = a_buf + (size_t)z*524288 + ((size_t)b*64 + sar)*128;
  const float* qrow = z ? (tgt + (size_t)b*128) : (q0 + ((size_t)b*64 + sar)*128);
  floatx16 c;
  g_gemm_h64(arow, qrow, W1fp + (size_t)z*98304, nq*64, pb, &c);
  c_write64(c, h1 + (size_t)z*1048576 + (size_t)b*16384 + nq*64, 256, 1);
}

// ===== K3: W2 GEMM + W3 dot + per-batch softmax (128 blocks: z,b) =====
__global__ __launch_bounds__(256) void k_w2(const float* __restrict__ h1, const float* __restrict__ W2,
                                            const float* __restrict__ W3, float* outF){
  __shared__ __align__(16) char POOL[46720];
  float* pf = (float*)POOL;
  __bf16* pb = (__bf16*)POOL;
  int blk = blockIdx.x, tid = threadIdx.x;
  int z = blk >> 6, b = blk & 63;
  const float* W2z = W2 + (size_t)z*32768;
  const float* W3z = W3 + z*128;
  floatx16 cA, cB;
  g_gemm(h1 + (size_t)z*1048576 + (size_t)b*64*256, 256, W2z, 128, 256, pb, &cA, &cB);
  int wv_ = tid >> 6, L = tid & 63, m = L & 31, half = L >> 5;
  int rB0 = (wv_ >> 1)*32 + m, rB1 = rB0 + 64;
  float wA = W3z[rB0], wB = W3z[rB1];
  float* lgp = pf + 11520;
  float c[16];
  #pragma unroll
  for (int reg = 0; reg < 16; reg++) c[reg] = lrelu(cA[reg])*wA + lrelu(cB[reg])*wB;
  #pragma unroll
  for (int off = 1; off < 32; off <<= 1)
    #pragma unroll
    for (int reg = 0; reg < 16; reg++) c[reg] += __shfl_xor(c[reg], off);
  if (m == 0){
    #pragma unroll
    for (int reg = 0; reg < 16; reg++) lgp[wv_*32 + half*16 + reg] = c[reg];
  }
  __syncthreads();
  if (tid < 64){
    int row = tid, wva = row >> 5, rem = row & 31;
    int hf = (rem >> 2) & 1, rg = (rem & 3) + 4*(rem >> 3);
    float l = lrelu(lgp[wva*32 + hf*16 + rg] + lgp[(wva + 2)*32 + hf*16 + rg]);
    float mx = l;
    #pragma unroll
    for (int off = 32; off; off >>= 1) mx = fmaxf(mx, __shfl_xor(mx, off));
    float e = expf(l - mx);
    float s = e;
    #pragma unroll
    for (int off = 32; off; off >>= 1) s += __shfl_xor(s, off);
    outF[z*4096 + b*64 + row] = e/s;
  }
}

// ===== K4: edge softmax + S + agg (64 blocks) =====
__global__ __launch_bounds__(256) void k_edge(const float* __restrict__ M_g, const float* __restrict__ fb,
                                              const float* __restrict__ x, float* __restrict__ S_g,
                                              float* __restrict__ agg){
  __shared__ __align__(16) float Mc[4096];
  __shared__ __align__(16) float xb[8192];
  __shared__ float f1s[64], f2s[64];
  int b = blockIdx.x, tid = threadIdx.x;
  for (int i = tid; i < 4096; i += 256) Mc[i] = M_g[b*4096 + i];
  for (int i = tid*4; i < 8192; i += 1024)
    *(float4*)&xb[i] = *(const float4*)(x + (size_t)b*8192 + i);
  if (tid < 64) f1s[tid] = fb[b*64 + tid];
  else if (tid < 128) f2s[tid - 64] = fb[4096 + b*64 + (tid - 64)];
  __syncthreads();
  int c = tid >> 2, sub = tid & 3;
  float m = -1e30f;
  for (int r = sub; r < 64; r += 4)
    if (Mc[r*64 + c] > 0.f) m = fmaxf(m, lrelu(f1s[c] + f2s[r]));
  m = fmaxf(m, __shfl_xor(m, 1));
  m = fmaxf(m, __shfl_xor(m, 2));
  float s = 0.f;
  for (int r = sub; r < 64; r += 4){
    float mc = Mc[r*64 + c];
    if (mc > 0.f) s += mc*expf(lrelu(f1s[c] + f2s[r]) - m);
  }
  s += __shfl_xor(s, 1);
  s += __shfl_xor(s, 2);
  for (int r = sub; r < 64; r += 4){
    float mc = Mc[r*64 + c];
    float v = 0.f;
    if (mc > 0.f) v = mc*expf(lrelu(f1s[c] + f2s[r]) - m)/s;
    Mc[r*64 + c] = v;
  }
  __syncthreads();
  for (int i = tid; i < 4096; i += 256) S_g[b*4096 + i] = Mc[i];
  int tc = (tid & 15)*4, tf = (tid >> 4)*8;
  float acc[4][8];
  #pragma unroll
  for (int i = 0; i < 4; i++)
    #pragma unroll
    for (int j = 0; j < 8; j++) acc[i][j] = 0.f;
  for (int r = 0; r < 64; r++){
    float4 e4 = *(const float4*)&Mc[r*64 + tc];
    float4 x0 = *(const float4*)&xb[r*128 + tf];
    float4 x1 = *(const float4*)&xb[r*128 + tf + 4];
    float e_[4] = {e4.x,e4.y,e4.z,e4.w};
    float x_[8] = {x0.x,x0.y,x0.z,x0.w,x1.x,x1.y,x1.z,x1.w};
    #pragma unroll
    for (int ci = 0; ci < 4; ci++)
      #pragma unroll
      for (int fj = 0; fj < 8; fj++) acc[ci][fj] += e_[ci]*x_[fj];
  }
  #pragma unroll
  for (int ci = 0; ci < 4; ci++){
    *(float4*)(agg + (size_t)b*8192 + (tc+ci)*128 + tf)     = make_float4(acc[ci][0],acc[ci][1],acc[ci][2],acc[ci][3]);
    *(float4*)(agg + (size_t)b*8192 + (tc+ci)*128 + tf + 4) = make_float4(acc[ci][4],acc[ci][5],acc[ci][6],acc[ci][7]);
  }
}

// ===== K5: lin (2 heads) + x_c + hop2(x_c) (64 blocks) =====
__global__ __launch_bounds__(256) void k_linxchop(const float* __restrict__ aggb, const float* __restrict__ x,
                                                  const float* __restrict__ linW, const float* __restrict__ A_g,
                                                  float* xcb, float* xq2){
  __shared__ __align__(16) char POOL[57856];
  float* pf = (float*)POOL;
  __bf16* pb = (__bf16*)POOL;
  int b = blockIdx.x, tid = threadIdx.x;
  floatx16 h0A, h0B, h1A, h1B2;
  g_gemm(aggb + (size_t)b*8192, 128, linW, 128, 128, pb, &h0A, &h0B);
  g_gemm(aggb + (size_t)b*8192, 128, linW + 16384, 128, 128, pb, &h1A, &h1B2);
  float* xcV = pf; float* Ab = pf + 8192; float* Tt = pf + 12288;
  {
    int wv_ = tid >> 6, L = tid & 63, m = L & 31, half = L >> 5;
    int rB0 = (wv_ >> 1)*32 + m, rB1 = rB0 + 64, row0 = 32*(wv_ & 1) + 4*half;
    #pragma unroll
    for (int reg = 0; reg < 16; reg++){
      int row = row0 + (reg & 3) + 8*(reg >> 2);
      float xv0 = x[((size_t)b*64 + row)*128 + rB0];
      float v0 = 0.5f*(lrelu(xv0 + h0A[reg]) + lrelu(xv0 + h1A[reg]));
      xcV[row*128 + rB0] = v0;
      xcb[(size_t)b*8192 + row*128 + rB0] = v0;
      float xv1 = x[((size_t)b*64 + row)*128 + rB1];
      float v1 = 0.5f*(lrelu(xv1 + h0B[reg]) + lrelu(xv1 + h1B2[reg]));
      xcV[row*128 + rB1] = v1;
      xcb[(size_t)b*8192 + row*128 + rB1] = v1;
    }
  }
  for (int i = tid*4; i < 4096; i += 1024)
    *(float4*)&Ab[i] = *(const float4*)(A_g + b*4096 + i);
  __syncthreads();
  hop2_run(Ab, xcV, nullptr, xq2 + (size_t)b*8192, Tt, Tt);
}

// ===== K6: Wk pair g (128 blocks: z,b) =====
__global__ __launch_bounds__(256) void k_wkg(const float* __restrict__ xcb, const float* __restrict__ Wkg,
                                             float* a_buf){
  __shared__ __align__(16) char POOL[46080];
  __bf16* pb = (__bf16*)POOL;
  int blk = blockIdx.x;
  int z = blk >> 6, b = blk & 63;
  floatx16 cA, cB;
  g_gemm(xcb + (size_t)b*8192, 128, Wkg + (size_t)z*16384, 128, 128, pb, &cA, &cB);
  c_write(cA, cB, a_buf + (size_t)z*524288 + (size_t)b*8192, 128, 0);
}

// ===== K7: pool (softmax + BITONIC top-52 + x_out/outB/outP) + C2 compute (64 blocks) =====
__global__ __launch_bounds__(256) void k_A2c(const float* __restrict__ gb, const float* __restrict__ x,
                                             const float* __restrict__ A_g, const float* __restrict__ S_g,
                                             float* C2g, float* outX, float* outB, float* outP){
  __shared__ __align__(16) float At[64*68];
  __shared__ __align__(16) float Sp[64*56];
  __shared__ __align__(16) float Tq[64*56];
  __shared__ int pi[64];
  __shared__ float pv[64];
  int b = blockIdx.x, tid = threadIdx.x;
  if (tid < 64){
    int lane = tid;
    float l = gb[b*64 + lane] + gb[4096 + b*64 + lane];
    float m = l;
    #pragma unroll
    for (int off = 32; off; off >>= 1) m = fmaxf(m, __shfl_xor(m, off));
    float e = expf(l - m);
    float sm = e;
    #pragma unroll
    for (int off = 32; off; off >>= 1) sm += __shfl_xor(sm, off);
    float v = e/sm;
    int idx = lane;
    #pragma unroll
    for (int k = 2; k <= 64; k <<= 1){
      #pragma unroll
      for (int j = k >> 1; j > 0; j >>= 1){
        float ov = __shfl_xor(v, j);
        int   oi = __shfl_xor(idx, j);
        bool ascBlock = (lane & k) == 0;
        bool iAmLow   = (lane & j) == 0;
        bool otherPrec = (ov > v) || (ov == v && oi < idx);
        bool take = (ascBlock == iAmLow) ? otherPrec : !otherPrec;
        if (take){ v = ov; idx = oi; }
      }
    }
    pi[lane] = idx; pv[lane] = v;
    if (lane < KK){
      outB[b*KK + lane] = (float)b;
      outP[b*KK + lane] = (float)(b*64 + idx);
    }
  }
  __syncthreads();
  for (int o = tid*4; o < KK*128; o += 1024){
    int j = o >> 7, f = o & 127;
    float4 xv = *(const float4*)(x + ((size_t)b*64 + pi[j])*128 + f);
    float sv = pv[j];
    *(float4*)(outX + (size_t)b*KK*128 + o) = make_float4(xv.x*sv, xv.y*sv, xv.z*sv, xv.w*sv);
  }
  for (int idx = tid; idx < 4096; idx += 256){
    int i = idx >> 6, k = idx & 63;
    At[k*68 + i] = A_g[b*4096 + idx];
  }
  for (int idx = tid; idx < 4096; idx += 256){
    int k = idx >> 6, t = idx & 63;
    if (t < 56) Sp[k*56 + t] = (t < KK) ? S_g[b*4096 + k*64 + pi[t]] : 0.f;
  }
  __syncthreads();
  if (tid < 224){
    int i0 = (tid/14)*4, t0 = (tid % 14)*4;
    float acc[4][4];
    #pragma unroll
    for (int a = 0; a < 4; a++)
      #pragma unroll
      for (int c = 0; c < 4; c++) acc[a][c] = 0.f;
    for (int k = 0; k < 64; k++){
      float4 a4 = *(const float4*)&At[k*68 + i0];
      float4 s4 = *(const float4*)&Sp[k*56 + t0];
      float a_[4] = {a4.x,a4.y,a4.z,a4.w};
      float s_[4] = {s4.x,s4.y,s4.z,s4.w};
      #pragma unroll
      for (int ii = 0; ii < 4; ii++)
        #pragma unroll
        for (int tt = 0; tt < 4; tt++) acc[ii][tt] += a_[ii]*s_[tt];
    }
    #pragma unroll
    for (int ii = 0; ii < 4; ii++)
      *(float4*)&Tq[(i0+ii)*56 + t0] = make_float4(acc[ii][0],acc[ii][1],acc[ii][2],acc[ii][3]);
  }
  __syncthreads();
  if (tid < 169){
    int a0 = (tid/13)*4, t0 = (tid % 13)*4;
    float acc[4][4];
    #pragma unroll
    for (int a = 0; a < 4; a++)
      #pragma unroll
      for (int c = 0; c < 4; c++) acc[a][c] = 0.f;
    for (int i = 0; i < 64; i++){
      float4 s4 = *(const float4*)&Sp[i*56 + a0];
      float4 t4 = *(const float4*)&Tq[i*56 + t0];
      float s_[4] = {s4.x,s4.y,s4.z,s4.w};
      float t_[4] = {t4.x,t4.y,t4.z,t4.w};
      #pragma unroll
      for (int aa = 0; aa < 4; aa++)
        #pragma unroll
        for (int tt = 0; tt < 4; tt++) acc[aa][tt] += s_[aa]*t_[tt];
    }
    #pragma unroll
    for (int aa = 0; aa < 4; aa++)
      #pragma unroll
      for (int tt = 0; tt < 4; tt++){
        int a = a0 + aa, t = t0 + tt;
        C2g[b*(KK*KK) + a*KK + t] = (a == t) ? 1.f : acc[aa][tt];
      }
  }
}

// ===== K8: bulk A2 write (10816 blocks, 1 float4/thread) =====
__global__ __launch_bounds__(256) void k_A2w(const float* __restrict__ C2g, float* __restrict__ outA2){
  int g = blockIdx.x*256 + threadIdx.x;      // 0 .. 2768895 (float4 index)
  int row = g/832, c4 = g - row*832;         // 832 float4 per row
  int b = row/KK, al = row - b*KK;
  int rel = c4 - b*13;
  float4 val;
  if (rel >= 0 && rel < 13){
    val = *(const float4*)(C2g + (size_t)b*(KK*KK) + al*KK + rel*4);
  } else {
    val = make_float4(0.f, 0.f, 0.f, 0.f);
  }
  *(float4*)(outA2 + (size_t)g*4) = val;
}

extern "C" void kernel_launch(void* const* d_in, const int* in_sizes, int n_in,
                              void* d_out, int out_size, void* d_ws, size_t ws_size,
                              hipStream_t stream){
  const float* x    = (const float*)d_in[0];
  const int*   ei   = (const int*)d_in[1];
  const float* ew   = (const float*)d_in[2];
  const float* tgt  = (const float*)d_in[3];
  const float* Wk   = (const float*)d_in[5];
  const float* W1   = (const float*)d_in[6];
  const float* W2   = (const float*)d_in[7];
  const float* W3   = (const float*)d_in[8];
  const float* linW = (const float*)d_in[9];
  float* out = (float*)d_out;

  float* wf   = (float*)d_ws;
  float* A_g  = wf;
  float* M_g  = wf + 262144;
  float* S_g  = wf + 524288;
  float* xq   = wf + 786432;
  float* xq2  = wf + 1310720;
  float* aggb = wf + 1835008;
  float* xcb  = wf + 2359296;
  float* a_buf= wf + 2883584;   // 2 x 524288
  float* h1   = wf + 3932160;   // 2 x 1048576
  float* fb   = wf + 6029312;   // 2 x 4096
  float* gb   = wf + 6037504;   // 2 x 4096
  float* W1f  = wf + 6045696;   // 4 x 98304 = 393216
  float* C2g  = wf + 6438912;   // 64 x 2704 = 173056

  float* outX  = out;
  float* outA2 = out + 425984;
  float* outB  = out + 425984 + 11075584;
  float* outP  = outB + NKOUT;

  // pair f (+ W1 pre-fold in spare blocks)
  k_p0<<<dim3(256), dim3(256), 0, stream>>>(ei, ew, x, Wk, W1, A_g, M_g, xq, a_buf, W1f);
  k_h1<<<dim3(512), dim3(256), 0, stream>>>(a_buf, xq, tgt, W1f, h1);
  k_w2<<<dim3(128), dim3(256), 0, stream>>>(h1, W2, W3, fb);
  // edge softmax + agg
  k_edge<<<dim3(64), dim3(256), 0, stream>>>(M_g, fb, x, S_g, aggb);
  // x_c + hop2
  k_linxchop<<<dim3(64), dim3(256), 0, stream>>>(aggb, x, linW, A_g, xcb, xq2);
  // pair g
  k_wkg<<<dim3(128), dim3(256), 0, stream>>>(xcb, Wk + 2*16384, a_buf);
  k_h1<<<dim3(512), dim3(256), 0, stream>>>(a_buf, xq2, tgt, W1f + 2*98304, h1);
  k_w2<<<dim3(128), dim3(256), 0, stream>>>(h1, W2 + 2*32768, W3 + 2*128, gb);
  // pool + C2 compute, then bulk A2 write
  k_A2c<<<dim3(64), dim3(256), 0, stream>>>(gb, x, A_g, S_g, C2g, outX, outB, outP);
  k_A2w<<<dim3(10816), dim3(256), 0, stream>>>(C2g, outA2);
}

// Round 12
// 241.267 us; speedup vs baseline: 1.1766x; 1.0675x over previous
//
#include <hip/hip_runtime.h>

// B=64 batches, n=64 nodes/batch, H=128, epg=2048 edges/batch
#define KK 52
#define NKOUT 3328
#define NEG 0.01f

typedef __attribute__((ext_vector_type(8))) __bf16 bf16x8;
typedef __attribute__((ext_vector_type(16))) float floatx16;

__device__ __forceinline__ float lrelu(float v){ return v > 0.f ? v : NEG*v; }

// LDS layout for MFMA chunks: row pitch 40 bf16 (80B); XOR swizzle on 16B chunks
#define SW(r, ko) ((r)*40 + ((ko) ^ ((((r)>>3)&3) << 3)))

__device__ __forceinline__ void split_store8(const float* vv, __bf16* P0, __bf16* P1, __bf16* P2, int addr){
  bf16x8 p1, p2, p3;
  #pragma unroll
  for (int j = 0; j < 8; j++){
    __bf16 b1 = (__bf16)vv[j];
    float r1 = vv[j] - (float)b1;
    __bf16 b2 = (__bf16)r1;
    float r2 = r1 - (float)b2;
    p1[j] = b1; p2[j] = b2; p3[j] = (__bf16)r2;
  }
  *(bf16x8*)(P0 + addr) = p1;
  *(bf16x8*)(P1 + addr) = p2;
  *(bf16x8*)(P2 + addr) = p3;
}

__device__ __forceinline__ void mfma6(const __bf16* A0, const __bf16* A1, const __bf16* A2,
                                      const __bf16* B0, const __bf16* B1, const __bf16* B2,
                                      int aoff, int boff, floatx16* acc){
  bf16x8 a1 = *(const bf16x8*)(A0 + aoff);
  bf16x8 a2 = *(const bf16x8*)(A1 + aoff);
  bf16x8 a3 = *(const bf16x8*)(A2 + aoff);
  bf16x8 b1 = *(const bf16x8*)(B0 + boff);
  bf16x8 b2 = *(const bf16x8*)(B1 + boff);
  bf16x8 b3 = *(const bf16x8*)(B2 + boff);
  floatx16 c = *acc;
  c = __builtin_amdgcn_mfma_f32_32x32x16_bf16(a1,b1,c,0,0,0);
  c = __builtin_amdgcn_mfma_f32_32x32x16_bf16(a1,b2,c,0,0,0);
  c = __builtin_amdgcn_mfma_f32_32x32x16_bf16(a2,b1,c,0,0,0);
  c = __builtin_amdgcn_mfma_f32_32x32x16_bf16(a1,b3,c,0,0,0);
  c = __builtin_amdgcn_mfma_f32_32x32x16_bf16(a3,b1,c,0,0,0);
  c = __builtin_amdgcn_mfma_f32_32x32x16_bf16(a2,b2,c,0,0,0);
  *acc = c;
}

// ---- generic 64x128 MFMA GEMM core (bf16x6 fp32-faithful), batched loads + reg prefetch ----
__device__ __forceinline__ void g_gemm(const float* __restrict__ A0, int ldA,
                                       const float* __restrict__ W0, int ldW, int K,
                                       __bf16* pb, floatx16* oA, floatx16* oB){
  __bf16 *As0 = pb, *As1 = pb+2560, *As2 = pb+5120;
  __bf16 *Bs0 = pb+7680, *Bs1 = pb+12800, *Bs2 = pb+17920;
  int tid = threadIdx.x;
  int sar = tid >> 2, sako = (tid & 3)*8;
  int bn = tid & 127, bk = (tid >> 7)*16;
  int wv_ = tid >> 6, L = tid & 63, m = L & 31, half = L >> 5;
  int rA = 32*(wv_ & 1) + m, rB0 = (wv_ >> 1)*32 + m, rB1 = rB0 + 64;
  const float* arow = A0 + (size_t)sar*ldA;
  floatx16 accA, accB;
  #pragma unroll
  for (int i = 0; i < 16; i++){ accA[i] = 0.f; accB[i] = 0.f; }
  float ra[8], wv[16];
  {
    float4 v0 = *(const float4*)(arow + sako);
    float4 v1 = *(const float4*)(arow + sako + 4);
    ra[0]=v0.x; ra[1]=v0.y; ra[2]=v0.z; ra[3]=v0.w; ra[4]=v1.x; ra[5]=v1.y; ra[6]=v1.z; ra[7]=v1.w;
    #pragma unroll
    for (int j = 0; j < 16; j++) wv[j] = W0[(size_t)(bk + j)*ldW + bn];
  }
  for (int k0 = 0; k0 < K; k0 += 32){
    split_store8(ra, As0, As1, As2, SW(sar, sako));
    split_store8(wv,     Bs0, Bs1, Bs2, SW(bn, bk));
    split_store8(wv + 8, Bs0, Bs1, Bs2, SW(bn, bk + 8));
    __syncthreads();
    int k1 = k0 + 32;
    float ra2[8], wv2[16];
    if (k1 < K){
      float4 v0 = *(const float4*)(arow + k1 + sako);
      float4 v1 = *(const float4*)(arow + k1 + sako + 4);
      ra2[0]=v0.x; ra2[1]=v0.y; ra2[2]=v0.z; ra2[3]=v0.w; ra2[4]=v1.x; ra2[5]=v1.y; ra2[6]=v1.z; ra2[7]=v1.w;
      #pragma unroll
      for (int j = 0; j < 16; j++) wv2[j] = W0[(size_t)(k1 + bk + j)*ldW + bn];
    }
    #pragma unroll
    for (int kg = 0; kg < 2; kg++){
      int ko = kg*16 + half*8;
      mfma6(As0,As1,As2, Bs0,Bs1,Bs2, SW(rA,ko), SW(rB0,ko), &accA);
      mfma6(As0,As1,As2, Bs0,Bs1,Bs2, SW(rA,ko), SW(rB1,ko), &accB);
    }
    __syncthreads();
    if (k1 < K){
      #pragma unroll
      for (int j = 0; j < 8; j++) ra[j] = ra2[j];
      #pragma unroll
      for (int j = 0; j < 16; j++) wv[j] = wv2[j];
    }
  }
  *oA = accA; *oB = accB;
}

// ---- generic 64x64-tile MFMA GEMM core (4 waves, one 32x32 quadrant each) ----
__device__ __forceinline__ void g_gemm64(const float* __restrict__ A0, int ldA,
                                         const float* __restrict__ W0, int ldW, int K,
                                         __bf16* pb, floatx16* oC){
  __bf16 *As0 = pb, *As1 = pb+2560, *As2 = pb+5120;
  __bf16 *Bs0 = pb+7680, *Bs1 = pb+10240, *Bs2 = pb+12800;
  int tid = threadIdx.x;
  int sar = tid >> 2, sako = (tid & 3)*8;
  int bn = tid & 63, bk = (tid >> 6)*8;
  int wv_ = tid >> 6, L = tid & 63, m = L & 31, half = L >> 5;
  int rA = 32*(wv_ & 1) + m, rB = 32*(wv_ >> 1) + m;
  const float* arow = A0 + (size_t)sar*ldA;
  floatx16 acc;
  #pragma unroll
  for (int i = 0; i < 16; i++) acc[i] = 0.f;
  float ra[8], wv[8];
  {
    float4 v0 = *(const float4*)(arow + sako);
    float4 v1 = *(const float4*)(arow + sako + 4);
    ra[0]=v0.x; ra[1]=v0.y; ra[2]=v0.z; ra[3]=v0.w; ra[4]=v1.x; ra[5]=v1.y; ra[6]=v1.z; ra[7]=v1.w;
    #pragma unroll
    for (int j = 0; j < 8; j++) wv[j] = W0[(size_t)(bk + j)*ldW + bn];
  }
  for (int k0 = 0; k0 < K; k0 += 32){
    split_store8(ra, As0, As1, As2, SW(sar, sako));
    split_store8(wv, Bs0, Bs1, Bs2, SW(bn, bk));
    __syncthreads();
    int k1 = k0 + 32;
    float ra2[8], wv2[8];
    if (k1 < K){
      float4 v0 = *(const float4*)(arow + k1 + sako);
      float4 v1 = *(const float4*)(arow + k1 + sako + 4);
      ra2[0]=v0.x; ra2[1]=v0.y; ra2[2]=v0.z; ra2[3]=v0.w; ra2[4]=v1.x; ra2[5]=v1.y; ra2[6]=v1.z; ra2[7]=v1.w;
      #pragma unroll
      for (int j = 0; j < 8; j++) wv2[j] = W0[(size_t)(k1 + bk + j)*ldW + bn];
    }
    #pragma unroll
    for (int kg = 0; kg < 2; kg++){
      int ko = kg*16 + half*8;
      mfma6(As0,As1,As2, Bs0,Bs1,Bs2, SW(rA,ko), SW(rB,ko), &acc);
    }
    __syncthreads();
    if (k1 < K){
      #pragma unroll
      for (int j = 0; j < 8; j++){ ra[j] = ra2[j]; wv[j] = wv2[j]; }
    }
  }
  *oC = acc;
}

// ---- 64x64-tile W1 GEMM core (K=384, pre-folded W1f, h=[a,q,a*q] synthesized) ----
__device__ __forceinline__ void g_gemm_h64(const float* __restrict__ arow, const float* __restrict__ qrow,
                                           const float* __restrict__ W1fz, int colbase,
                                           __bf16* pb, floatx16* oC){
  __bf16 *As0 = pb, *As1 = pb+2560, *As2 = pb+5120;
  __bf16 *Bs0 = pb+7680, *Bs1 = pb+10240, *Bs2 = pb+12800;
  int tid = threadIdx.x;
  int sar = tid >> 2, sako = (tid & 3)*8;
  int bn = tid & 63, bk = (tid >> 6)*8;
  int col = colbase + bn;
  int wv_ = tid >> 6, L = tid & 63, m = L & 31, half = L >> 5;
  int rA = 32*(wv_ & 1) + m, rB = 32*(wv_ >> 1) + m;
  auto loadA = [&](int k0, float* r){
    int seg = k0 >> 7, kl = (k0 & 127) + sako;
    if (seg == 0){
      float4 a0 = *(const float4*)(arow + kl), a1 = *(const float4*)(arow + kl + 4);
      r[0]=a0.x; r[1]=a0.y; r[2]=a0.z; r[3]=a0.w; r[4]=a1.x; r[5]=a1.y; r[6]=a1.z; r[7]=a1.w;
    } else if (seg == 1){
      float4 q0 = *(const float4*)(qrow + kl), q1 = *(const float4*)(qrow + kl + 4);
      r[0]=q0.x; r[1]=q0.y; r[2]=q0.z; r[3]=q0.w; r[4]=q1.x; r[5]=q1.y; r[6]=q1.z; r[7]=q1.w;
    } else {
      float4 a0 = *(const float4*)(arow + kl), a1 = *(const float4*)(arow + kl + 4);
      float4 q0 = *(const float4*)(qrow + kl), q1 = *(const float4*)(qrow + kl + 4);
      r[0]=a0.x*q0.x; r[1]=a0.y*q0.y; r[2]=a0.z*q0.z; r[3]=a0.w*q0.w;
      r[4]=a1.x*q1.x; r[5]=a1.y*q1.y; r[6]=a1.z*q1.z; r[7]=a1.w*q1.w;
    }
  };
  auto loadB = [&](int k0, float* r){
    #pragma unroll
    for (int j = 0; j < 8; j++) r[j] = W1fz[(size_t)(k0 + bk + j)*256 + col];
  };
  floatx16 acc;
  #pragma unroll
  for (int i = 0; i < 16; i++) acc[i] = 0.f;
  float ra[8], wv[8];
  loadA(0, ra); loadB(0, wv);
  for (int k0 = 0; k0 < 384; k0 += 32){
    split_store8(ra, As0, As1, As2, SW(sar, sako));
    split_store8(wv, Bs0, Bs1, Bs2, SW(bn, bk));
    __syncthreads();
    int k1 = k0 + 32;
    float ra2[8], wv2[8];
    if (k1 < 384){ loadA(k1, ra2); loadB(k1, wv2); }
    #pragma unroll
    for (int kg = 0; kg < 2; kg++){
      int ko = kg*16 + half*8;
      mfma6(As0,As1,As2, Bs0,Bs1,Bs2, SW(rA,ko), SW(rB,ko), &acc);
    }
    __syncthreads();
    if (k1 < 384){
      #pragma unroll
      for (int j = 0; j < 8; j++){ ra[j] = ra2[j]; wv[j] = wv2[j]; }
    }
  }
  *oC = acc;
}

__device__ __forceinline__ void c_write(floatx16 accA, floatx16 accB, float* C0, int ldC, int act){
  int tid = threadIdx.x, wv_ = tid >> 6, L = tid & 63, m = L & 31, half = L >> 5;
  int rB0 = (wv_ >> 1)*32 + m, rB1 = rB0 + 64;
  int row0 = 32*(wv_ & 1) + 4*half;
  #pragma unroll
  for (int reg = 0; reg < 16; reg++){
    int row = row0 + (reg & 3) + 8*(reg >> 2);
    float va = accA[reg], vb = accB[reg];
    if (act){ va = lrelu(va); vb = lrelu(vb); }
    C0[(size_t)row*ldC + rB0] = va;
    C0[(size_t)row*ldC + rB1] = vb;
  }
}

__device__ __forceinline__ void c_write64(floatx16 acc, float* C0, int ldC, int act){
  int tid = threadIdx.x, wv_ = tid >> 6, L = tid & 63, m = L & 31, half = L >> 5;
  int col = 32*(wv_ >> 1) + m;
  int row0 = 32*(wv_ & 1) + 4*half;
  #pragma unroll
  for (int reg = 0; reg < 16; reg++){
    int row = row0 + (reg & 3) + 8*(reg >> 2);
    float v = acc[reg];
    if (act) v = lrelu(v);
    C0[(size_t)row*ldC + col] = v;
  }
}

// ---- double hop (A^T twice), A in LDS; src either global rows or LDS 64x128 ----
__device__ __forceinline__ void hop2_run(const float* A, const float* VfullL,
                                         const float* srcG, float* dstG,
                                         float* Vt, float* Tt){
  int tid = threadIdx.x;
  int tc = (tid & 31)*2, tf = (tid >> 5)*4;
  for (int f0 = 0; f0 < 128; f0 += 32){
    if (!VfullL){
      for (int o = tid; o < 2048; o += 256){
        int r = o >> 5, f = o & 31;
        Vt[o] = srcG[r*128 + f0 + f];
      }
      __syncthreads();
    }
    float a00,a01,a02,a03,a10,a11,a12,a13;
    a00=a01=a02=a03=a10=a11=a12=a13=0.f;
    for (int r = 0; r < 64; r++){
      float x0 = A[r*64 + tc], x1 = A[r*64 + tc + 1];
      float4 v4 = VfullL ? *(const float4*)&VfullL[r*128 + f0 + tf]
                         : *(const float4*)&Vt[r*32 + tf];
      a00 += x0*v4.x; a01 += x0*v4.y; a02 += x0*v4.z; a03 += x0*v4.w;
      a10 += x1*v4.x; a11 += x1*v4.y; a12 += x1*v4.z; a13 += x1*v4.w;
    }
    *(float4*)&Tt[tc*32 + tf]     = make_float4(a00,a01,a02,a03);
    *(float4*)&Tt[(tc+1)*32 + tf] = make_float4(a10,a11,a12,a13);
    __syncthreads();
    a00=a01=a02=a03=a10=a11=a12=a13=0.f;
    for (int r = 0; r < 64; r++){
      float x0 = A[r*64 + tc], x1 = A[r*64 + tc + 1];
      float4 v4 = *(const float4*)&Tt[r*32 + tf];
      a00 += x0*v4.x; a01 += x0*v4.y; a02 += x0*v4.z; a03 += x0*v4.w;
      a10 += x1*v4.x; a11 += x1*v4.y; a12 += x1*v4.z; a13 += x1*v4.w;
    }
    *(float4*)(dstG + tc*128 + f0 + tf)     = make_float4(a00,a01,a02,a03);
    *(float4*)(dstG + (tc+1)*128 + f0 + tf) = make_float4(a10,a11,a12,a13);
    __syncthreads();
  }
}

// ===== K1: build+hop2 (blk<64) || Wk-f (64..191) || W1 fold (192..255) || A2 zero-fill (256..2959) =====
__global__ __launch_bounds__(256) void k_p0(const int* __restrict__ ei, const float* __restrict__ ew,
                                            const float* __restrict__ x, const float* __restrict__ Wk,
                                            const float* __restrict__ W1,
                                            float* A_g, float* M_g, float* xq, float* a_buf, float* W1f,
                                            float* outA2){
  __shared__ __align__(16) char POOL[57856];
  float* pf = (float*)POOL;
  __bf16* pb = (__bf16*)POOL;
  int blk = blockIdx.x, tid = threadIdx.x;
  if (blk < 64){
    int b = blk;
    float* Ws = pf; float* Mc = pf + 4096; float* dv = pf + 8192;
    for (int i = tid; i < 4096; i += 256){ Ws[i] = 0.f; Mc[i] = 0.f; }
    __syncthreads();
    const int* r0 = ei + b*2048;
    const int* c0 = ei + 64*2048 + b*2048;
    const float* w0 = ew + b*2048;
    int base = b*64;
    for (int e = tid; e < 2048; e += 256){
      int r = r0[e] - base, c = c0[e] - base;
      atomicAdd(&Ws[r*64 + c], w0[e]);
      atomicAdd(&Mc[r*64 + c], 1.f);
    }
    if (tid < 64){ atomicAdd(&Ws[tid*65], 1.f); atomicAdd(&Mc[tid*65], 1.f); }
    __syncthreads();
    if (tid < 64){
      float d = 0.f;
      for (int r = 0; r < 64; r++) d += Ws[r*64 + tid];
      dv[tid] = d > 0.f ? rsqrtf(fmaxf(d, 1e-12f)) : 0.f;
    }
    __syncthreads();
    for (int i = tid; i < 4096; i += 256){
      int r = i >> 6, c = i & 63;
      float a = dv[r]*Ws[i]*dv[c];
      Ws[i] = a;
      A_g[b*4096 + i] = a;
      M_g[b*4096 + i] = Mc[i];
    }
    __syncthreads();
    hop2_run(Ws, nullptr, x + (size_t)b*8192, xq + (size_t)b*8192, pf + 8256, pf + 10304);
  } else if (blk < 192){
    int idx = blk - 64, z = idx >> 6, b = idx & 63;
    floatx16 cA, cB;
    g_gemm(x + (size_t)b*8192, 128, Wk + (size_t)z*16384, 128, 128, pb, &cA, &cB);
    c_write(cA, cB, a_buf + (size_t)z*524288 + (size_t)b*8192, 128, 0);
  } else if (blk < 256){
    // fold W1 (all 4 heads) -> W1f[head][384][256]
    int idx0 = (blk - 192)*6144;
    for (int i = tid; i < 6144; i += 256){
      int g = idx0 + i;
      int zz = g / 98304;
      int r = g - zz*98304;
      int kr = r >> 8, c = r & 255;
      const float* Wz = W1 + (size_t)zz*131072;
      float v;
      if (kr < 128)       v = Wz[kr*256 + c] + Wz[(kr + 256)*256 + c];
      else if (kr < 256)  v = Wz[kr*256 + c] - Wz[(kr + 128)*256 + c];
      else                v = Wz[(kr + 128)*256 + c];
      W1f[g] = v;
    }
  } else {
    // zero-fill full A2 region (44.3 MB); nonzero blocks overwritten later by k_A2c
    float4* p = (float4*)outA2;
    int base = (blk - 256)*1024 + tid;
    #pragma unroll
    for (int i = 0; i < 4; i++) p[base + i*256] = make_float4(0.f,0.f,0.f,0.f);
  }
}

// ===== K2: W1 fold GEMM (512 blocks: b,z,nq) — 64x64 tiles, 2 blocks/CU =====
__global__ __launch_bounds__(256) void k_h1(const float* __restrict__ a_buf, const float* __restrict__ q0,
                                            const float* __restrict__ tgt, const float* __restrict__ W1fp,
                                            float* h1){
  __shared__ __align__(16) char POOL[30720];
  __bf16* pb = (__bf16*)POOL;
  int blk = blockIdx.x, tid = threadIdx.x;
  int b = blk >> 3, z = (blk >> 2) & 1, nq = blk & 3;
  int sar = tid >> 2;
  const float* arow = a_buf + (size_t)z*524288 + ((size_t)b*64 + sar)*128;
  const float* qrow = z ? (tgt + (size_t)b*128) : (q0 + ((size_t)b*64 + sar)*128);
  floatx16 c;
  g_gemm_h64(arow, qrow, W1fp + (size_t)z*98304, nq*64, pb, &c);
  c_write64(c, h1 + (size_t)z*1048576 + (size_t)b*16384 + nq*64, 256, 1);
}

// ===== K3: W2 partial-logit GEMM (256 blocks: b,z,nh) — 64x64 tiles, partial W3 dot =====
// lp[slot][b*64+row], slot = z*2+nh; consumer computes lrelu(p0+p1) and softmax.
__global__ __launch_bounds__(256) void k_w2p(const float* __restrict__ h1, const float* __restrict__ W2,
                                             const float* __restrict__ W3, float* __restrict__ lp){
  __shared__ __align__(16) char POOL[30720];
  __shared__ float lgp[128];
  __bf16* pb = (__bf16*)POOL;
  int blk = blockIdx.x, tid = threadIdx.x;
  int b = blk >> 2, z = (blk >> 1) & 1, nh = blk & 1;
  floatx16 c;
  g_gemm64(h1 + (size_t)z*1048576 + (size_t)b*16384, 256,
           W2 + (size_t)z*32768 + nh*64, 128, 256, pb, &c);
  int wv_ = tid >> 6, L = tid & 63, m = L & 31, half = L >> 5;
  int col = 32*(wv_ >> 1) + m;
  float w = W3[z*128 + nh*64 + col];
  float v[16];
  #pragma unroll
  for (int reg = 0; reg < 16; reg++) v[reg] = lrelu(c[reg])*w;
  #pragma unroll
  for (int off = 1; off < 32; off <<= 1)
    #pragma unroll
    for (int reg = 0; reg < 16; reg++) v[reg] += __shfl_xor(v[reg], off);
  if (m == 0){
    #pragma unroll
    for (int reg = 0; reg < 16; reg++) lgp[wv_*32 + half*16 + reg] = v[reg];
  }
  __syncthreads();
  if (tid < 64){
    int row = tid, rh = row >> 5, rem = row & 31;
    int hf = (rem >> 2) & 1, rg = (rem & 3) + 4*(rem >> 3);
    float p = lgp[rh*32 + hf*16 + rg] + lgp[(rh + 2)*32 + hf*16 + rg];
    lp[(z*2 + nh)*4096 + b*64 + row] = p;
  }
}

// ===== K4: edge softmax + S + agg (64 blocks) — computes f softmaxes from lp partials =====
__global__ __launch_bounds__(256) void k_edge(const float* __restrict__ M_g, const float* __restrict__ lp,
                                              const float* __restrict__ x, float* __restrict__ S_g,
                                              float* __restrict__ agg){
  __shared__ __align__(16) float Mc[4096];
  __shared__ __align__(16) float xb[8192];
  __shared__ float f1s[64], f2s[64];
  int b = blockIdx.x, tid = threadIdx.x;
  for (int i = tid; i < 4096; i += 256) Mc[i] = M_g[b*4096 + i];
  for (int i = tid*4; i < 8192; i += 1024)
    *(float4*)&xb[i] = *(const float4*)(x + (size_t)b*8192 + i);
  if (tid < 128){
    int z = tid >> 6, r = tid & 63;
    float d = lp[(z*2)*4096 + b*64 + r] + lp[(z*2 + 1)*4096 + b*64 + r];
    float l = lrelu(d);
    float mx = l;
    #pragma unroll
    for (int off = 32; off; off >>= 1) mx = fmaxf(mx, __shfl_xor(mx, off));
    float e = expf(l - mx);
    float s = e;
    #pragma unroll
    for (int off = 32; off; off >>= 1) s += __shfl_xor(s, off);
    (z ? f2s : f1s)[r] = e/s;
  }
  __syncthreads();
  int c = tid >> 2, sub = tid & 3;
  float m = -1e30f;
  for (int r = sub; r < 64; r += 4)
    if (Mc[r*64 + c] > 0.f) m = fmaxf(m, lrelu(f1s[c] + f2s[r]));
  m = fmaxf(m, __shfl_xor(m, 1));
  m = fmaxf(m, __shfl_xor(m, 2));
  float s = 0.f;
  for (int r = sub; r < 64; r += 4){
    float mc = Mc[r*64 + c];
    if (mc > 0.f) s += mc*expf(lrelu(f1s[c] + f2s[r]) - m);
  }
  s += __shfl_xor(s, 1);
  s += __shfl_xor(s, 2);
  for (int r = sub; r < 64; r += 4){
    float mc = Mc[r*64 + c];
    float v = 0.f;
    if (mc > 0.f) v = mc*expf(lrelu(f1s[c] + f2s[r]) - m)/s;
    Mc[r*64 + c] = v;
  }
  __syncthreads();
  for (int i = tid; i < 4096; i += 256) S_g[b*4096 + i] = Mc[i];
  int tc = (tid & 15)*4, tf = (tid >> 4)*8;
  float acc[4][8];
  #pragma unroll
  for (int i = 0; i < 4; i++)
    #pragma unroll
    for (int j = 0; j < 8; j++) acc[i][j] = 0.f;
  for (int r = 0; r < 64; r++){
    float4 e4 = *(const float4*)&Mc[r*64 + tc];
    float4 x0 = *(const float4*)&xb[r*128 + tf];
    float4 x1 = *(const float4*)&xb[r*128 + tf + 4];
    float e_[4] = {e4.x,e4.y,e4.z,e4.w};
    float x_[8] = {x0.x,x0.y,x0.z,x0.w,x1.x,x1.y,x1.z,x1.w};
    #pragma unroll
    for (int ci = 0; ci < 4; ci++)
      #pragma unroll
      for (int fj = 0; fj < 8; fj++) acc[ci][fj] += e_[ci]*x_[fj];
  }
  #pragma unroll
  for (int ci = 0; ci < 4; ci++){
    *(float4*)(agg + (size_t)b*8192 + (tc+ci)*128 + tf)     = make_float4(acc[ci][0],acc[ci][1],acc[ci][2],acc[ci][3]);
    *(float4*)(agg + (size_t)b*8192 + (tc+ci)*128 + tf + 4) = make_float4(acc[ci][4],acc[ci][5],acc[ci][6],acc[ci][7]);
  }
}

// ===== K5: lin (2 heads) + x_c + hop2(x_c) (64 blocks) =====
__global__ __launch_bounds__(256) void k_linxchop(const float* __restrict__ aggb, const float* __restrict__ x,
                                                  const float* __restrict__ linW, const float* __restrict__ A_g,
                                                  float* xcb, float* xq2){
  __shared__ __align__(16) char POOL[57856];
  float* pf = (float*)POOL;
  __bf16* pb = (__bf16*)POOL;
  int b = blockIdx.x, tid = threadIdx.x;
  floatx16 h0A, h0B, h1A, h1B2;
  g_gemm(aggb + (size_t)b*8192, 128, linW, 128, 128, pb, &h0A, &h0B);
  g_gemm(aggb + (size_t)b*8192, 128, linW + 16384, 128, 128, pb, &h1A, &h1B2);
  float* xcV = pf; float* Ab = pf + 8192; float* Tt = pf + 12288;
  {
    int wv_ = tid >> 6, L = tid & 63, m = L & 31, half = L >> 5;
    int rB0 = (wv_ >> 1)*32 + m, rB1 = rB0 + 64, row0 = 32*(wv_ & 1) + 4*half;
    #pragma unroll
    for (int reg = 0; reg < 16; reg++){
      int row = row0 + (reg & 3) + 8*(reg >> 2);
      float xv0 = x[((size_t)b*64 + row)*128 + rB0];
      float v0 = 0.5f*(lrelu(xv0 + h0A[reg]) + lrelu(xv0 + h1A[reg]));
      xcV[row*128 + rB0] = v0;
      xcb[(size_t)b*8192 + row*128 + rB0] = v0;
      float xv1 = x[((size_t)b*64 + row)*128 + rB1];
      float v1 = 0.5f*(lrelu(xv1 + h0B[reg]) + lrelu(xv1 + h1B2[reg]));
      xcV[row*128 + rB1] = v1;
      xcb[(size_t)b*8192 + row*128 + rB1] = v1;
    }
  }
  for (int i = tid*4; i < 4096; i += 1024)
    *(float4*)&Ab[i] = *(const float4*)(A_g + b*4096 + i);
  __syncthreads();
  hop2_run(Ab, xcV, nullptr, xq2 + (size_t)b*8192, Tt, Tt);
}

// ===== K6: Wk pair g (256 blocks: b,z,nh) — 64x64 tiles =====
__global__ __launch_bounds__(256) void k_wkg(const float* __restrict__ xcb, const float* __restrict__ Wkg,
                                             float* a_buf){
  __shared__ __align__(16) char POOL[30720];
  __bf16* pb = (__bf16*)POOL;
  int blk = blockIdx.x;
  int b = blk >> 2, z = (blk >> 1) & 1, nh = blk & 1;
  floatx16 c;
  g_gemm64(xcb + (size_t)b*8192, 128, Wkg + (size_t)z*16384 + nh*64, 128, 128, pb, &c);
  c_write64(c, a_buf + (size_t)z*524288 + (size_t)b*8192 + nh*64, 128, 0);
}

// ===== K7: pool (softmaxes from lp + bitonic top-52 + x_out) + direct A2 block writes (64 blocks) =====
__global__ __launch_bounds__(256) void k_A2c(const float* __restrict__ lp, const float* __restrict__ x,
                                             const float* __restrict__ A_g, const float* __restrict__ S_g,
                                             float* outA2, float* outX, float* outB, float* outP){
  __shared__ __align__(16) float At[64*68];
  __shared__ __align__(16) float Sp[64*56];
  __shared__ __align__(16) float Tq[64*56];
  __shared__ int pi[64];
  __shared__ float pv[64];
  int b = blockIdx.x, tid = threadIdx.x;
  if (tid < 64){
    int lane = tid;
    // g1 = softmax_batch(lrelu(p0+p1)) for z=0; g2 likewise for z=1
    float f[2];
    #pragma unroll
    for (int z = 0; z < 2; z++){
      float d = lp[(z*2)*4096 + b*64 + lane] + lp[(z*2 + 1)*4096 + b*64 + lane];
      float l = lrelu(d);
      float mx = l;
      #pragma unroll
      for (int off = 32; off; off >>= 1) mx = fmaxf(mx, __shfl_xor(mx, off));
      float e = expf(l - mx);
      float sm = e;
      #pragma unroll
      for (int off = 32; off; off >>= 1) sm += __shfl_xor(sm, off);
      f[z] = e/sm;
    }
    float l = f[0] + f[1];
    float m = l;
    #pragma unroll
    for (int off = 32; off; off >>= 1) m = fmaxf(m, __shfl_xor(m, off));
    float e = expf(l - m);
    float sm = e;
    #pragma unroll
    for (int off = 32; off; off >>= 1) sm += __shfl_xor(sm, off);
    float v = e/sm;
    int idx = lane;
    #pragma unroll
    for (int k = 2; k <= 64; k <<= 1){
      #pragma unroll
      for (int j = k >> 1; j > 0; j >>= 1){
        float ov = __shfl_xor(v, j);
        int   oi = __shfl_xor(idx, j);
        bool ascBlock = (lane & k) == 0;
        bool iAmLow   = (lane & j) == 0;
        bool otherPrec = (ov > v) || (ov == v && oi < idx);
        bool take = (ascBlock == iAmLow) ? otherPrec : !otherPrec;
        if (take){ v = ov; idx = oi; }
      }
    }
    pi[lane] = idx; pv[lane] = v;
    if (lane < KK){
      outB[b*KK + lane] = (float)b;
      outP[b*KK + lane] = (float)(b*64 + idx);
    }
  }
  __syncthreads();
  for (int o = tid*4; o < KK*128; o += 1024){
    int j = o >> 7, f = o & 127;
    float4 xv = *(const float4*)(x + ((size_t)b*64 + pi[j])*128 + f);
    float sv = pv[j];
    *(float4*)(outX + (size_t)b*KK*128 + o) = make_float4(xv.x*sv, xv.y*sv, xv.z*sv, xv.w*sv);
  }
  for (int idx = tid; idx < 4096; idx += 256){
    int i = idx >> 6, k = idx & 63;
    At[k*68 + i] = A_g[b*4096 + idx];
  }
  for (int idx = tid; idx < 4096; idx += 256){
    int k = idx >> 6, t = idx & 63;
    if (t < 56) Sp[k*56 + t] = (t < KK) ? S_g[b*4096 + k*64 + pi[t]] : 0.f;
  }
  __syncthreads();
  if (tid < 224){
    int i0 = (tid/14)*4, t0 = (tid % 14)*4;
    float acc[4][4];
    #pragma unroll
    for (int a = 0; a < 4; a++)
      #pragma unroll
      for (int c = 0; c < 4; c++) acc[a][c] = 0.f;
    for (int k = 0; k < 64; k++){
      float4 a4 = *(const float4*)&At[k*68 + i0];
      float4 s4 = *(const float4*)&Sp[k*56 + t0];
      float a_[4] = {a4.x,a4.y,a4.z,a4.w};
      float s_[4] = {s4.x,s4.y,s4.z,s4.w};
      #pragma unroll
      for (int ii = 0; ii < 4; ii++)
        #pragma unroll
        for (int tt = 0; tt < 4; tt++) acc[ii][tt] += a_[ii]*s_[tt];
    }
    #pragma unroll
    for (int ii = 0; ii < 4; ii++)
      *(float4*)&Tq[(i0+ii)*56 + t0] = make_float4(acc[ii][0],acc[ii][1],acc[ii][2],acc[ii][3]);
  }
  __syncthreads();
  if (tid < 169){
    int a0 = (tid/13)*4, t0 = (tid % 13)*4;
    float acc[4][4];
    #pragma unroll
    for (int a = 0; a < 4; a++)
      #pragma unroll
      for (int c = 0; c < 4; c++) acc[a][c] = 0.f;
    for (int i = 0; i < 64; i++){
      float4 s4 = *(const float4*)&Sp[i*56 + a0];
      float4 t4 = *(const float4*)&Tq[i*56 + t0];
      float s_[4] = {s4.x,s4.y,s4.z,s4.w};
      float t_[4] = {t4.x,t4.y,t4.z,t4.w};
      #pragma unroll
      for (int aa = 0; aa < 4; aa++)
        #pragma unroll
        for (int tt = 0; tt < 4; tt++) acc[aa][tt] += s_[aa]*t_[tt];
    }
    #pragma unroll
    for (int aa = 0; aa < 4; aa++){
      int a = a0 + aa;
      float4 o;
      o.x = (a == t0    ) ? 1.f : acc[aa][0];
      o.y = (a == t0 + 1) ? 1.f : acc[aa][1];
      o.z = (a == t0 + 2) ? 1.f : acc[aa][2];
      o.w = (a == t0 + 3) ? 1.f : acc[aa][3];
      *(float4*)(outA2 + (size_t)(b*KK + a)*NKOUT + b*KK + t0) = o;
    }
  }
}

extern "C" void kernel_launch(void* const* d_in, const int* in_sizes, int n_in,
                              void* d_out, int out_size, void* d_ws, size_t ws_size,
                              hipStream_t stream){
  const float* x    = (const float*)d_in[0];
  const int*   ei   = (const int*)d_in[1];
  const float* ew   = (const float*)d_in[2];
  const float* tgt  = (const float*)d_in[3];
  const float* Wk   = (const float*)d_in[5];
  const float* W1   = (const float*)d_in[6];
  const float* W2   = (const float*)d_in[7];
  const float* W3   = (const float*)d_in[8];
  const float* linW = (const float*)d_in[9];
  float* out = (float*)d_out;

  float* wf   = (float*)d_ws;
  float* A_g  = wf;
  float* M_g  = wf + 262144;
  float* S_g  = wf + 524288;
  float* xq   = wf + 786432;
  float* xq2  = wf + 1310720;
  float* aggb = wf + 1835008;
  float* xcb  = wf + 2359296;
  float* a_buf= wf + 2883584;   // 2 x 524288
  float* h1   = wf + 3932160;   // 2 x 1048576
  float* lp   = wf + 6029312;   // 4 x 4096 partial logits
  float* W1f  = wf + 6045696;   // 4 x 98304 = 393216

  float* outX  = out;
  float* outA2 = out + 425984;
  float* outB  = out + 425984 + 11075584;
  float* outP  = outB + NKOUT;

  // pair f (+ W1 pre-fold + A2 zero-fill in spare blocks)
  k_p0<<<dim3(2960), dim3(256), 0, stream>>>(ei, ew, x, Wk, W1, A_g, M_g, xq, a_buf, W1f, outA2);
  k_h1<<<dim3(512), dim3(256), 0, stream>>>(a_buf, xq, tgt, W1f, h1);
  k_w2p<<<dim3(256), dim3(256), 0, stream>>>(h1, W2, W3, lp);
  // edge softmax + agg (computes f softmaxes from lp)
  k_edge<<<dim3(64), dim3(256), 0, stream>>>(M_g, lp, x, S_g, aggb);
  // x_c + hop2
  k_linxchop<<<dim3(64), dim3(256), 0, stream>>>(aggb, x, linW, A_g, xcb, xq2);
  // pair g
  k_wkg<<<dim3(256), dim3(256), 0, stream>>>(xcb, Wk + 2*16384, a_buf);
  k_h1<<<dim3(512), dim3(256), 0, stream>>>(a_buf, xq2, tgt, W1f + 2*98304, h1);
  k_w2p<<<dim3(256), dim3(256), 0, stream>>>(h1, W2 + 2*32768, W3 + 2*128, lp);
  // pool + direct A2 block writes
  k_A2c<<<dim3(64), dim3(256), 0, stream>>>(lp, x, A_g, S_g, outA2, outX, outB, outP);
}

// Round 13
// 227.755 us; speedup vs baseline: 1.2464x; 1.0593x over previous
//
#include <hip/hip_runtime.h>

// B=64 batches, n=64 nodes/batch, H=128, epg=2048 edges/batch
#define KK 52
#define NKOUT 3328
#define NEG 0.01f

typedef __attribute__((ext_vector_type(8))) __bf16 bf16x8;
typedef __attribute__((ext_vector_type(16))) float floatx16;

__device__ __forceinline__ float lrelu(float v){ return v > 0.f ? v : NEG*v; }

// LDS layout for MFMA chunks: row pitch 40 bf16 (80B); XOR swizzle on 16B chunks
#define SW(r, ko) ((r)*40 + ((ko) ^ ((((r)>>3)&3) << 3)))

__device__ __forceinline__ void split_store8(const float* vv, __bf16* P0, __bf16* P1, __bf16* P2, int addr){
  bf16x8 p1, p2, p3;
  #pragma unroll
  for (int j = 0; j < 8; j++){
    __bf16 b1 = (__bf16)vv[j];
    float r1 = vv[j] - (float)b1;
    __bf16 b2 = (__bf16)r1;
    float r2 = r1 - (float)b2;
    p1[j] = b1; p2[j] = b2; p3[j] = (__bf16)r2;
  }
  *(bf16x8*)(P0 + addr) = p1;
  *(bf16x8*)(P1 + addr) = p2;
  *(bf16x8*)(P2 + addr) = p3;
}

__device__ __forceinline__ void mfma6(const __bf16* A0, const __bf16* A1, const __bf16* A2,
                                      const __bf16* B0, const __bf16* B1, const __bf16* B2,
                                      int aoff, int boff, floatx16* acc){
  bf16x8 a1 = *(const bf16x8*)(A0 + aoff);
  bf16x8 a2 = *(const bf16x8*)(A1 + aoff);
  bf16x8 a3 = *(const bf16x8*)(A2 + aoff);
  bf16x8 b1 = *(const bf16x8*)(B0 + boff);
  bf16x8 b2 = *(const bf16x8*)(B1 + boff);
  bf16x8 b3 = *(const bf16x8*)(B2 + boff);
  floatx16 c = *acc;
  c = __builtin_amdgcn_mfma_f32_32x32x16_bf16(a1,b1,c,0,0,0);
  c = __builtin_amdgcn_mfma_f32_32x32x16_bf16(a1,b2,c,0,0,0);
  c = __builtin_amdgcn_mfma_f32_32x32x16_bf16(a2,b1,c,0,0,0);
  c = __builtin_amdgcn_mfma_f32_32x32x16_bf16(a1,b3,c,0,0,0);
  c = __builtin_amdgcn_mfma_f32_32x32x16_bf16(a3,b1,c,0,0,0);
  c = __builtin_amdgcn_mfma_f32_32x32x16_bf16(a2,b2,c,0,0,0);
  *acc = c;
}

// ---- generic 64x128 MFMA GEMM core (bf16x6 fp32-faithful), batched loads + reg prefetch ----
// A0 may point to global or LDS (generic pointer).
__device__ __forceinline__ void g_gemm(const float* A0, int ldA,
                                       const float* __restrict__ W0, int ldW, int K,
                                       __bf16* pb, floatx16* oA, floatx16* oB){
  __bf16 *As0 = pb, *As1 = pb+2560, *As2 = pb+5120;
  __bf16 *Bs0 = pb+7680, *Bs1 = pb+12800, *Bs2 = pb+17920;
  int tid = threadIdx.x;
  int sar = tid >> 2, sako = (tid & 3)*8;
  int bn = tid & 127, bk = (tid >> 7)*16;
  int wv_ = tid >> 6, L = tid & 63, m = L & 31, half = L >> 5;
  int rA = 32*(wv_ & 1) + m, rB0 = (wv_ >> 1)*32 + m, rB1 = rB0 + 64;
  const float* arow = A0 + (size_t)sar*ldA;
  floatx16 accA, accB;
  #pragma unroll
  for (int i = 0; i < 16; i++){ accA[i] = 0.f; accB[i] = 0.f; }
  float ra[8], wv[16];
  {
    float4 v0 = *(const float4*)(arow + sako);
    float4 v1 = *(const float4*)(arow + sako + 4);
    ra[0]=v0.x; ra[1]=v0.y; ra[2]=v0.z; ra[3]=v0.w; ra[4]=v1.x; ra[5]=v1.y; ra[6]=v1.z; ra[7]=v1.w;
    #pragma unroll
    for (int j = 0; j < 16; j++) wv[j] = W0[(size_t)(bk + j)*ldW + bn];
  }
  for (int k0 = 0; k0 < K; k0 += 32){
    split_store8(ra, As0, As1, As2, SW(sar, sako));
    split_store8(wv,     Bs0, Bs1, Bs2, SW(bn, bk));
    split_store8(wv + 8, Bs0, Bs1, Bs2, SW(bn, bk + 8));
    __syncthreads();
    int k1 = k0 + 32;
    float ra2[8], wv2[16];
    if (k1 < K){
      float4 v0 = *(const float4*)(arow + k1 + sako);
      float4 v1 = *(const float4*)(arow + k1 + sako + 4);
      ra2[0]=v0.x; ra2[1]=v0.y; ra2[2]=v0.z; ra2[3]=v0.w; ra2[4]=v1.x; ra2[5]=v1.y; ra2[6]=v1.z; ra2[7]=v1.w;
      #pragma unroll
      for (int j = 0; j < 16; j++) wv2[j] = W0[(size_t)(k1 + bk + j)*ldW + bn];
    }
    #pragma unroll
    for (int kg = 0; kg < 2; kg++){
      int ko = kg*16 + half*8;
      mfma6(As0,As1,As2, Bs0,Bs1,Bs2, SW(rA,ko), SW(rB0,ko), &accA);
      mfma6(As0,As1,As2, Bs0,Bs1,Bs2, SW(rA,ko), SW(rB1,ko), &accB);
    }
    __syncthreads();
    if (k1 < K){
      #pragma unroll
      for (int j = 0; j < 8; j++) ra[j] = ra2[j];
      #pragma unroll
      for (int j = 0; j < 16; j++) wv[j] = wv2[j];
    }
  }
  *oA = accA; *oB = accB;
}

// ---- generic 64x64-tile MFMA GEMM core (4 waves, one 32x32 quadrant each) ----
__device__ __forceinline__ void g_gemm64(const float* __restrict__ A0, int ldA,
                                         const float* __restrict__ W0, int ldW, int K,
                                         __bf16* pb, floatx16* oC){
  __bf16 *As0 = pb, *As1 = pb+2560, *As2 = pb+5120;
  __bf16 *Bs0 = pb+7680, *Bs1 = pb+10240, *Bs2 = pb+12800;
  int tid = threadIdx.x;
  int sar = tid >> 2, sako = (tid & 3)*8;
  int bn = tid & 63, bk = (tid >> 6)*8;
  int wv_ = tid >> 6, L = tid & 63, m = L & 31, half = L >> 5;
  int rA = 32*(wv_ & 1) + m, rB = 32*(wv_ >> 1) + m;
  const float* arow = A0 + (size_t)sar*ldA;
  floatx16 acc;
  #pragma unroll
  for (int i = 0; i < 16; i++) acc[i] = 0.f;
  float ra[8], wv[8];
  {
    float4 v0 = *(const float4*)(arow + sako);
    float4 v1 = *(const float4*)(arow + sako + 4);
    ra[0]=v0.x; ra[1]=v0.y; ra[2]=v0.z; ra[3]=v0.w; ra[4]=v1.x; ra[5]=v1.y; ra[6]=v1.z; ra[7]=v1.w;
    #pragma unroll
    for (int j = 0; j < 8; j++) wv[j] = W0[(size_t)(bk + j)*ldW + bn];
  }
  for (int k0 = 0; k0 < K; k0 += 32){
    split_store8(ra, As0, As1, As2, SW(sar, sako));
    split_store8(wv, Bs0, Bs1, Bs2, SW(bn, bk));
    __syncthreads();
    int k1 = k0 + 32;
    float ra2[8], wv2[8];
    if (k1 < K){
      float4 v0 = *(const float4*)(arow + k1 + sako);
      float4 v1 = *(const float4*)(arow + k1 + sako + 4);
      ra2[0]=v0.x; ra2[1]=v0.y; ra2[2]=v0.z; ra2[3]=v0.w; ra2[4]=v1.x; ra2[5]=v1.y; ra2[6]=v1.z; ra2[7]=v1.w;
      #pragma unroll
      for (int j = 0; j < 8; j++) wv2[j] = W0[(size_t)(k1 + bk + j)*ldW + bn];
    }
    #pragma unroll
    for (int kg = 0; kg < 2; kg++){
      int ko = kg*16 + half*8;
      mfma6(As0,As1,As2, Bs0,Bs1,Bs2, SW(rA,ko), SW(rB,ko), &acc);
    }
    __syncthreads();
    if (k1 < K){
      #pragma unroll
      for (int j = 0; j < 8; j++){ ra[j] = ra2[j]; wv[j] = wv2[j]; }
    }
  }
  *oC = acc;
}

// ---- 64x64-tile W1 GEMM core (K=384, pre-folded W1f, h=[a,q,a*q] synthesized) ----
__device__ __forceinline__ void g_gemm_h64(const float* __restrict__ arow, const float* __restrict__ qrow,
                                           const float* __restrict__ W1fz, int colbase,
                                           __bf16* pb, floatx16* oC){
  __bf16 *As0 = pb, *As1 = pb+2560, *As2 = pb+5120;
  __bf16 *Bs0 = pb+7680, *Bs1 = pb+10240, *Bs2 = pb+12800;
  int tid = threadIdx.x;
  int sar = tid >> 2, sako = (tid & 3)*8;
  int bn = tid & 63, bk = (tid >> 6)*8;
  int col = colbase + bn;
  int wv_ = tid >> 6, L = tid & 63, m = L & 31, half = L >> 5;
  int rA = 32*(wv_ & 1) + m, rB = 32*(wv_ >> 1) + m;
  auto loadA = [&](int k0, float* r){
    int seg = k0 >> 7, kl = (k0 & 127) + sako;
    if (seg == 0){
      float4 a0 = *(const float4*)(arow + kl), a1 = *(const float4*)(arow + kl + 4);
      r[0]=a0.x; r[1]=a0.y; r[2]=a0.z; r[3]=a0.w; r[4]=a1.x; r[5]=a1.y; r[6]=a1.z; r[7]=a1.w;
    } else if (seg == 1){
      float4 q0 = *(const float4*)(qrow + kl), q1 = *(const float4*)(qrow + kl + 4);
      r[0]=q0.x; r[1]=q0.y; r[2]=q0.z; r[3]=q0.w; r[4]=q1.x; r[5]=q1.y; r[6]=q1.z; r[7]=q1.w;
    } else {
      float4 a0 = *(const float4*)(arow + kl), a1 = *(const float4*)(arow + kl + 4);
      float4 q0 = *(const float4*)(qrow + kl), q1 = *(const float4*)(qrow + kl + 4);
      r[0]=a0.x*q0.x; r[1]=a0.y*q0.y; r[2]=a0.z*q0.z; r[3]=a0.w*q0.w;
      r[4]=a1.x*q1.x; r[5]=a1.y*q1.y; r[6]=a1.z*q1.z; r[7]=a1.w*q1.w;
    }
  };
  auto loadB = [&](int k0, float* r){
    #pragma unroll
    for (int j = 0; j < 8; j++) r[j] = W1fz[(size_t)(k0 + bk + j)*256 + col];
  };
  floatx16 acc;
  #pragma unroll
  for (int i = 0; i < 16; i++) acc[i] = 0.f;
  float ra[8], wv[8];
  loadA(0, ra); loadB(0, wv);
  for (int k0 = 0; k0 < 384; k0 += 32){
    split_store8(ra, As0, As1, As2, SW(sar, sako));
    split_store8(wv, Bs0, Bs1, Bs2, SW(bn, bk));
    __syncthreads();
    int k1 = k0 + 32;
    float ra2[8], wv2[8];
    if (k1 < 384){ loadA(k1, ra2); loadB(k1, wv2); }
    #pragma unroll
    for (int kg = 0; kg < 2; kg++){
      int ko = kg*16 + half*8;
      mfma6(As0,As1,As2, Bs0,Bs1,Bs2, SW(rA,ko), SW(rB,ko), &acc);
    }
    __syncthreads();
    if (k1 < 384){
      #pragma unroll
      for (int j = 0; j < 8; j++){ ra[j] = ra2[j]; wv[j] = wv2[j]; }
    }
  }
  *oC = acc;
}

__device__ __forceinline__ void c_write(floatx16 accA, floatx16 accB, float* C0, int ldC, int act){
  int tid = threadIdx.x, wv_ = tid >> 6, L = tid & 63, m = L & 31, half = L >> 5;
  int rB0 = (wv_ >> 1)*32 + m, rB1 = rB0 + 64;
  int row0 = 32*(wv_ & 1) + 4*half;
  #pragma unroll
  for (int reg = 0; reg < 16; reg++){
    int row = row0 + (reg & 3) + 8*(reg >> 2);
    float va = accA[reg], vb = accB[reg];
    if (act){ va = lrelu(va); vb = lrelu(vb); }
    C0[(size_t)row*ldC + rB0] = va;
    C0[(size_t)row*ldC + rB1] = vb;
  }
}

__device__ __forceinline__ void c_write64(floatx16 acc, float* C0, int ldC, int act){
  int tid = threadIdx.x, wv_ = tid >> 6, L = tid & 63, m = L & 31, half = L >> 5;
  int col = 32*(wv_ >> 1) + m;
  int row0 = 32*(wv_ & 1) + 4*half;
  #pragma unroll
  for (int reg = 0; reg < 16; reg++){
    int row = row0 + (reg & 3) + 8*(reg >> 2);
    float v = acc[reg];
    if (act) v = lrelu(v);
    C0[(size_t)row*ldC + col] = v;
  }
}

// ---- double hop (A^T twice), A in LDS; src either global rows or LDS 64x128; f-range selectable ----
__device__ __forceinline__ void hop2_run(const float* A, const float* VfullL,
                                         const float* srcG, float* dstG,
                                         float* Vt, float* Tt, int fbeg, int fend){
  int tid = threadIdx.x;
  int tc = (tid & 31)*2, tf = (tid >> 5)*4;
  for (int f0 = fbeg; f0 < fend; f0 += 32){
    if (!VfullL){
      for (int o = tid; o < 2048; o += 256){
        int r = o >> 5, f = o & 31;
        Vt[o] = srcG[r*128 + f0 + f];
      }
      __syncthreads();
    }
    float a00,a01,a02,a03,a10,a11,a12,a13;
    a00=a01=a02=a03=a10=a11=a12=a13=0.f;
    for (int r = 0; r < 64; r++){
      float x0 = A[r*64 + tc], x1 = A[r*64 + tc + 1];
      float4 v4 = VfullL ? *(const float4*)&VfullL[r*128 + f0 + tf]
                         : *(const float4*)&Vt[r*32 + tf];
      a00 += x0*v4.x; a01 += x0*v4.y; a02 += x0*v4.z; a03 += x0*v4.w;
      a10 += x1*v4.x; a11 += x1*v4.y; a12 += x1*v4.z; a13 += x1*v4.w;
    }
    *(float4*)&Tt[tc*32 + tf]     = make_float4(a00,a01,a02,a03);
    *(float4*)&Tt[(tc+1)*32 + tf] = make_float4(a10,a11,a12,a13);
    __syncthreads();
    a00=a01=a02=a03=a10=a11=a12=a13=0.f;
    for (int r = 0; r < 64; r++){
      float x0 = A[r*64 + tc], x1 = A[r*64 + tc + 1];
      float4 v4 = *(const float4*)&Tt[r*32 + tf];
      a00 += x0*v4.x; a01 += x0*v4.y; a02 += x0*v4.z; a03 += x0*v4.w;
      a10 += x1*v4.x; a11 += x1*v4.y; a12 += x1*v4.z; a13 += x1*v4.w;
    }
    *(float4*)(dstG + tc*128 + f0 + tf)     = make_float4(a00,a01,a02,a03);
    *(float4*)(dstG + (tc+1)*128 + f0 + tf) = make_float4(a10,a11,a12,a13);
    __syncthreads();
  }
}

// ===== K1: build+hop2 f-split (blk<128) || Wk-f (128..255) || W1 fold (256..319) || A2 zero (320..3023) =====
__global__ __launch_bounds__(256) void k_p0(const int* __restrict__ ei, const float* __restrict__ ew,
                                            const float* __restrict__ x, const float* __restrict__ Wk,
                                            const float* __restrict__ W1,
                                            float* A_g, float* M_g, float* xq, float* a_buf, float* W1f,
                                            float* outA2){
  __shared__ __align__(16) char POOL[57856];
  float* pf = (float*)POOL;
  __bf16* pb = (__bf16*)POOL;
  int blk = blockIdx.x, tid = threadIdx.x;
  if (blk < 128){
    int b = blk >> 1, fh = blk & 1;
    float* Ws = pf; float* Mc = pf + 4096; float* dv = pf + 8192;
    for (int i = tid; i < 4096; i += 256){ Ws[i] = 0.f; Mc[i] = 0.f; }
    __syncthreads();
    const int* r0 = ei + b*2048;
    const int* c0 = ei + 64*2048 + b*2048;
    const float* w0 = ew + b*2048;
    int base = b*64;
    for (int e = tid; e < 2048; e += 256){
      int r = r0[e] - base, c = c0[e] - base;
      atomicAdd(&Ws[r*64 + c], w0[e]);
      atomicAdd(&Mc[r*64 + c], 1.f);
    }
    if (tid < 64){ atomicAdd(&Ws[tid*65], 1.f); atomicAdd(&Mc[tid*65], 1.f); }
    __syncthreads();
    if (tid < 64){
      float d = 0.f;
      for (int r = 0; r < 64; r++) d += Ws[r*64 + tid];
      dv[tid] = d > 0.f ? rsqrtf(fmaxf(d, 1e-12f)) : 0.f;
    }
    __syncthreads();
    for (int i = tid; i < 4096; i += 256){
      int r = i >> 6, c = i & 63;
      float a = dv[r]*Ws[i]*dv[c];
      Ws[i] = a;
      if (fh == 0){
        A_g[b*4096 + i] = a;
        M_g[b*4096 + i] = Mc[i];
      }
    }
    __syncthreads();
    hop2_run(Ws, nullptr, x + (size_t)b*8192, xq + (size_t)b*8192, pf + 8256, pf + 10304,
             fh*64, fh*64 + 64);
  } else if (blk < 256){
    int idx = blk - 128, z = idx >> 6, b = idx & 63;
    floatx16 cA, cB;
    g_gemm(x + (size_t)b*8192, 128, Wk + (size_t)z*16384, 128, 128, pb, &cA, &cB);
    c_write(cA, cB, a_buf + (size_t)z*524288 + (size_t)b*8192, 128, 0);
  } else if (blk < 320){
    // fold W1 (all 4 heads) -> W1f[head][384][256]
    int idx0 = (blk - 256)*6144;
    for (int i = tid; i < 6144; i += 256){
      int g = idx0 + i;
      int zz = g / 98304;
      int r = g - zz*98304;
      int kr = r >> 8, c = r & 255;
      const float* Wz = W1 + (size_t)zz*131072;
      float v;
      if (kr < 128)       v = Wz[kr*256 + c] + Wz[(kr + 256)*256 + c];
      else if (kr < 256)  v = Wz[kr*256 + c] - Wz[(kr + 128)*256 + c];
      else                v = Wz[(kr + 128)*256 + c];
      W1f[g] = v;
    }
  } else {
    // zero-fill full A2 region (44.3 MB); nonzero blocks overwritten later by k_A2c
    float4* p = (float4*)outA2;
    int base = (blk - 320)*1024 + tid;
    #pragma unroll
    for (int i = 0; i < 4; i++) p[base + i*256] = make_float4(0.f,0.f,0.f,0.f);
  }
}

// ===== K2: W1 fold GEMM (512 blocks: b,z,nq) — 64x64 tiles, 2 blocks/CU =====
__global__ __launch_bounds__(256) void k_h1(const float* __restrict__ a_buf, const float* __restrict__ q0,
                                            const float* __restrict__ tgt, const float* __restrict__ W1fp,
                                            float* h1){
  __shared__ __align__(16) char POOL[30720];
  __bf16* pb = (__bf16*)POOL;
  int blk = blockIdx.x, tid = threadIdx.x;
  int b = blk >> 3, z = (blk >> 2) & 1, nq = blk & 3;
  int sar = tid >> 2;
  const float* arow = a_buf + (size_t)z*524288 + ((size_t)b*64 + sar)*128;
  const float* qrow = z ? (tgt + (size_t)b*128) : (q0 + ((size_t)b*64 + sar)*128);
  floatx16 c;
  g_gemm_h64(arow, qrow, W1fp + (size_t)z*98304, nq*64, pb, &c);
  c_write64(c, h1 + (size_t)z*1048576 + (size_t)b*16384 + nq*64, 256, 1);
}

// ===== K3: W2 partial-logit GEMM (256 blocks: b,z,nh) — 64x64 tiles, partial W3 dot =====
__global__ __launch_bounds__(256) void k_w2p(const float* __restrict__ h1, const float* __restrict__ W2,
                                             const float* __restrict__ W3, float* __restrict__ lp){
  __shared__ __align__(16) char POOL[30720];
  __shared__ float lgp[128];
  __bf16* pb = (__bf16*)POOL;
  int blk = blockIdx.x, tid = threadIdx.x;
  int b = blk >> 2, z = (blk >> 1) & 1, nh = blk & 1;
  floatx16 c;
  g_gemm64(h1 + (size_t)z*1048576 + (size_t)b*16384, 256,
           W2 + (size_t)z*32768 + nh*64, 128, 256, pb, &c);
  int wv_ = tid >> 6, L = tid & 63, m = L & 31, half = L >> 5;
  int col = 32*(wv_ >> 1) + m;
  float w = W3[z*128 + nh*64 + col];
  float v[16];
  #pragma unroll
  for (int reg = 0; reg < 16; reg++) v[reg] = lrelu(c[reg])*w;
  #pragma unroll
  for (int off = 1; off < 32; off <<= 1)
    #pragma unroll
    for (int reg = 0; reg < 16; reg++) v[reg] += __shfl_xor(v[reg], off);
  if (m == 0){
    #pragma unroll
    for (int reg = 0; reg < 16; reg++) lgp[wv_*32 + half*16 + reg] = v[reg];
  }
  __syncthreads();
  if (tid < 64){
    int row = tid, rh = row >> 5, rem = row & 31;
    int hf = (rem >> 2) & 1, rg = (rem & 3) + 4*(rem >> 3);
    float p = lgp[rh*32 + hf*16 + rg] + lgp[(rh + 2)*32 + hf*16 + rg];
    lp[(z*2 + nh)*4096 + b*64 + row] = p;
  }
}

// ===== K4 (fused): edge softmax + S + agg(LDS) + lin + x_c + hop2 (64 blocks) =====
__global__ __launch_bounds__(256) void k_edgelin(const float* __restrict__ M_g, const float* __restrict__ lp,
                                                 const float* __restrict__ x, const float* __restrict__ linW,
                                                 const float* __restrict__ A_g,
                                                 float* S_g, float* xcb, float* xq2){
  __shared__ __align__(16) char POOL[128512];
  __bf16* pb = (__bf16*)POOL;                  // GEMM staging (46080 B), later Ab/Tt
  float* f1s = (float*)(POOL + 46080);         // 64
  float* f2s = (float*)(POOL + 46336);         // 64
  float* Mc  = (float*)(POOL + 46592);         // 4096
  float* xb  = (float*)(POOL + 62976);         // 8192 (x; later x_c in-place)
  float* aggL= (float*)(POOL + 95744);         // 8192
  int b = blockIdx.x, tid = threadIdx.x;
  for (int i = tid; i < 4096; i += 256) Mc[i] = M_g[b*4096 + i];
  for (int i = tid*4; i < 8192; i += 1024)
    *(float4*)&xb[i] = *(const float4*)(x + (size_t)b*8192 + i);
  if (tid < 128){
    int z = tid >> 6, r = tid & 63;
    float d = lp[(z*2)*4096 + b*64 + r] + lp[(z*2 + 1)*4096 + b*64 + r];
    float l = lrelu(d);
    float mx = l;
    #pragma unroll
    for (int off = 32; off; off >>= 1) mx = fmaxf(mx, __shfl_xor(mx, off));
    float e = expf(l - mx);
    float s = e;
    #pragma unroll
    for (int off = 32; off; off >>= 1) s += __shfl_xor(s, off);
    (z ? f2s : f1s)[r] = e/s;
  }
  __syncthreads();
  {
    int c = tid >> 2, sub = tid & 3;
    float m = -1e30f;
    for (int r = sub; r < 64; r += 4)
      if (Mc[r*64 + c] > 0.f) m = fmaxf(m, lrelu(f1s[c] + f2s[r]));
    m = fmaxf(m, __shfl_xor(m, 1));
    m = fmaxf(m, __shfl_xor(m, 2));
    float s = 0.f;
    for (int r = sub; r < 64; r += 4){
      float mc = Mc[r*64 + c];
      if (mc > 0.f) s += mc*expf(lrelu(f1s[c] + f2s[r]) - m);
    }
    s += __shfl_xor(s, 1);
    s += __shfl_xor(s, 2);
    for (int r = sub; r < 64; r += 4){
      float mc = Mc[r*64 + c];
      float v = 0.f;
      if (mc > 0.f) v = mc*expf(lrelu(f1s[c] + f2s[r]) - m)/s;
      Mc[r*64 + c] = v;
    }
  }
  __syncthreads();
  for (int i = tid; i < 4096; i += 256) S_g[b*4096 + i] = Mc[i];
  {
    int tc = (tid & 15)*4, tf = (tid >> 4)*8;
    float acc[4][8];
    #pragma unroll
    for (int i = 0; i < 4; i++)
      #pragma unroll
      for (int j = 0; j < 8; j++) acc[i][j] = 0.f;
    for (int r = 0; r < 64; r++){
      float4 e4 = *(const float4*)&Mc[r*64 + tc];
      float4 x0 = *(const float4*)&xb[r*128 + tf];
      float4 x1 = *(const float4*)&xb[r*128 + tf + 4];
      float e_[4] = {e4.x,e4.y,e4.z,e4.w};
      float x_[8] = {x0.x,x0.y,x0.z,x0.w,x1.x,x1.y,x1.z,x1.w};
      #pragma unroll
      for (int ci = 0; ci < 4; ci++)
        #pragma unroll
        for (int fj = 0; fj < 8; fj++) acc[ci][fj] += e_[ci]*x_[fj];
    }
    #pragma unroll
    for (int ci = 0; ci < 4; ci++){
      *(float4*)&aggL[(tc+ci)*128 + tf]     = make_float4(acc[ci][0],acc[ci][1],acc[ci][2],acc[ci][3]);
      *(float4*)&aggL[(tc+ci)*128 + tf + 4] = make_float4(acc[ci][4],acc[ci][5],acc[ci][6],acc[ci][7]);
    }
  }
  __syncthreads();
  // lin GEMMs (A from LDS aggL; staging in pb)
  floatx16 h0A, h0B, h1A, h1B2;
  g_gemm(aggL, 128, linW, 128, 128, pb, &h0A, &h0B);
  g_gemm(aggL, 128, linW + 16384, 128, 128, pb, &h1A, &h1B2);
  // x_c: read x from LDS xb, write x_c in-place (each slot touched by exactly one thread)
  {
    int wv_ = tid >> 6, L = tid & 63, m = L & 31, half = L >> 5;
    int rB0 = (wv_ >> 1)*32 + m, rB1 = rB0 + 64, row0 = 32*(wv_ & 1) + 4*half;
    #pragma unroll
    for (int reg = 0; reg < 16; reg++){
      int row = row0 + (reg & 3) + 8*(reg >> 2);
      float xv0 = xb[row*128 + rB0];
      float v0 = 0.5f*(lrelu(xv0 + h0A[reg]) + lrelu(xv0 + h1A[reg]));
      xb[row*128 + rB0] = v0;
      xcb[(size_t)b*8192 + row*128 + rB0] = v0;
      float xv1 = xb[row*128 + rB1];
      float v1 = 0.5f*(lrelu(xv1 + h0B[reg]) + lrelu(xv1 + h1B2[reg]));
      xb[row*128 + rB1] = v1;
      xcb[(size_t)b*8192 + row*128 + rB1] = v1;
    }
  }
  // hop2(x_c): Ab/Tt overlap the (now dead) staging region
  float* Ab = (float*)POOL;
  float* Tt = (float*)(POOL + 16384);
  for (int i = tid*4; i < 4096; i += 1024)
    *(float4*)&Ab[i] = *(const float4*)(A_g + b*4096 + i);
  __syncthreads();
  hop2_run(Ab, xb, nullptr, xq2 + (size_t)b*8192, Tt, Tt, 0, 128);
}

// ===== K5: Wk pair g (256 blocks: b,z,nh) — 64x64 tiles =====
__global__ __launch_bounds__(256) void k_wkg(const float* __restrict__ xcb, const float* __restrict__ Wkg,
                                             float* a_buf){
  __shared__ __align__(16) char POOL[30720];
  __bf16* pb = (__bf16*)POOL;
  int blk = blockIdx.x;
  int b = blk >> 2, z = (blk >> 1) & 1, nh = blk & 1;
  floatx16 c;
  g_gemm64(xcb + (size_t)b*8192, 128, Wkg + (size_t)z*16384 + nh*64, 128, 128, pb, &c);
  c_write64(c, a_buf + (size_t)z*524288 + (size_t)b*8192 + nh*64, 128, 0);
}

// ===== K6: pool (softmaxes from lp + bitonic top-52 + x_out) + direct A2 block writes (64 blocks) =====
__global__ __launch_bounds__(256) void k_A2c(const float* __restrict__ lp, const float* __restrict__ x,
                                             const float* __restrict__ A_g, const float* __restrict__ S_g,
                                             float* outA2, float* outX, float* outB, float* outP){
  __shared__ __align__(16) float At[64*68];
  __shared__ __align__(16) float Sp[64*56];
  __shared__ __align__(16) float Tq[64*56];
  __shared__ int pi[64];
  __shared__ float pv[64];
  int b = blockIdx.x, tid = threadIdx.x;
  if (tid < 64){
    int lane = tid;
    float f[2];
    #pragma unroll
    for (int z = 0; z < 2; z++){
      float d = lp[(z*2)*4096 + b*64 + lane] + lp[(z*2 + 1)*4096 + b*64 + lane];
      float l = lrelu(d);
      float mx = l;
      #pragma unroll
      for (int off = 32; off; off >>= 1) mx = fmaxf(mx, __shfl_xor(mx, off));
      float e = expf(l - mx);
      float sm = e;
      #pragma unroll
      for (int off = 32; off; off >>= 1) sm += __shfl_xor(sm, off);
      f[z] = e/sm;
    }
    float l = f[0] + f[1];
    float m = l;
    #pragma unroll
    for (int off = 32; off; off >>= 1) m = fmaxf(m, __shfl_xor(m, off));
    float e = expf(l - m);
    float sm = e;
    #pragma unroll
    for (int off = 32; off; off >>= 1) sm += __shfl_xor(sm, off);
    float v = e/sm;
    int idx = lane;
    #pragma unroll
    for (int k = 2; k <= 64; k <<= 1){
      #pragma unroll
      for (int j = k >> 1; j > 0; j >>= 1){
        float ov = __shfl_xor(v, j);
        int   oi = __shfl_xor(idx, j);
        bool ascBlock = (lane & k) == 0;
        bool iAmLow   = (lane & j) == 0;
        bool otherPrec = (ov > v) || (ov == v && oi < idx);
        bool take = (ascBlock == iAmLow) ? otherPrec : !otherPrec;
        if (take){ v = ov; idx = oi; }
      }
    }
    pi[lane] = idx; pv[lane] = v;
    if (lane < KK){
      outB[b*KK + lane] = (float)b;
      outP[b*KK + lane] = (float)(b*64 + idx);
    }
  }
  __syncthreads();
  for (int o = tid*4; o < KK*128; o += 1024){
    int j = o >> 7, f = o & 127;
    float4 xv = *(const float4*)(x + ((size_t)b*64 + pi[j])*128 + f);
    float sv = pv[j];
    *(float4*)(outX + (size_t)b*KK*128 + o) = make_float4(xv.x*sv, xv.y*sv, xv.z*sv, xv.w*sv);
  }
  for (int idx = tid; idx < 4096; idx += 256){
    int i = idx >> 6, k = idx & 63;
    At[k*68 + i] = A_g[b*4096 + idx];
  }
  for (int idx = tid; idx < 4096; idx += 256){
    int k = idx >> 6, t = idx & 63;
    if (t < 56) Sp[k*56 + t] = (t < KK) ? S_g[b*4096 + k*64 + pi[t]] : 0.f;
  }
  __syncthreads();
  if (tid < 224){
    int i0 = (tid/14)*4, t0 = (tid % 14)*4;
    float acc[4][4];
    #pragma unroll
    for (int a = 0; a < 4; a++)
      #pragma unroll
      for (int c = 0; c < 4; c++) acc[a][c] = 0.f;
    for (int k = 0; k < 64; k++){
      float4 a4 = *(const float4*)&At[k*68 + i0];
      float4 s4 = *(const float4*)&Sp[k*56 + t0];
      float a_[4] = {a4.x,a4.y,a4.z,a4.w};
      float s_[4] = {s4.x,s4.y,s4.z,s4.w};
      #pragma unroll
      for (int ii = 0; ii < 4; ii++)
        #pragma unroll
        for (int tt = 0; tt < 4; tt++) acc[ii][tt] += a_[ii]*s_[tt];
    }
    #pragma unroll
    for (int ii = 0; ii < 4; ii++)
      *(float4*)&Tq[(i0+ii)*56 + t0] = make_float4(acc[ii][0],acc[ii][1],acc[ii][2],acc[ii][3]);
  }
  __syncthreads();
  if (tid < 169){
    int a0 = (tid/13)*4, t0 = (tid % 13)*4;
    float acc[4][4];
    #pragma unroll
    for (int a = 0; a < 4; a++)
      #pragma unroll
      for (int c = 0; c < 4; c++) acc[a][c] = 0.f;
    for (int i = 0; i < 64; i++){
      float4 s4 = *(const float4*)&Sp[i*56 + a0];
      float4 t4 = *(const float4*)&Tq[i*56 + t0];
      float s_[4] = {s4.x,s4.y,s4.z,s4.w};
      float t_[4] = {t4.x,t4.y,t4.z,t4.w};
      #pragma unroll
      for (int aa = 0; aa < 4; aa++)
        #pragma unroll
        for (int tt = 0; tt < 4; tt++) acc[aa][tt] += s_[aa]*t_[tt];
    }
    #pragma unroll
    for (int aa = 0; aa < 4; aa++){
      int a = a0 + aa;
      float4 o;
      o.x = (a == t0    ) ? 1.f : acc[aa][0];
      o.y = (a == t0 + 1) ? 1.f : acc[aa][1];
      o.z = (a == t0 + 2) ? 1.f : acc[aa][2];
      o.w = (a == t0 + 3) ? 1.f : acc[aa][3];
      *(float4*)(outA2 + (size_t)(b*KK + a)*NKOUT + b*KK + t0) = o;
    }
  }
}

extern "C" void kernel_launch(void* const* d_in, const int* in_sizes, int n_in,
                              void* d_out, int out_size, void* d_ws, size_t ws_size,
                              hipStream_t stream){
  const float* x    = (const float*)d_in[0];
  const int*   ei   = (const int*)d_in[1];
  const float* ew   = (const float*)d_in[2];
  const float* tgt  = (const float*)d_in[3];
  const float* Wk   = (const float*)d_in[5];
  const float* W1   = (const float*)d_in[6];
  const float* W2   = (const float*)d_in[7];
  const float* W3   = (const float*)d_in[8];
  const float* linW = (const float*)d_in[9];
  float* out = (float*)d_out;

  float* wf   = (float*)d_ws;
  float* A_g  = wf;
  float* M_g  = wf + 262144;
  float* S_g  = wf + 524288;
  float* xq   = wf + 786432;
  float* xq2  = wf + 1310720;
  float* xcb  = wf + 2359296;
  float* a_buf= wf + 2883584;   // 2 x 524288
  float* h1   = wf + 3932160;   // 2 x 1048576
  float* lp   = wf + 6029312;   // 4 x 4096 partial logits
  float* W1f  = wf + 6045696;   // 4 x 98304 = 393216

  float* outX  = out;
  float* outA2 = out + 425984;
  float* outB  = out + 425984 + 11075584;
  float* outP  = outB + NKOUT;

  // pair f (+ W1 pre-fold + A2 zero-fill in spare blocks; build/hop f-split over 128 blocks)
  k_p0<<<dim3(3024), dim3(256), 0, stream>>>(ei, ew, x, Wk, W1, A_g, M_g, xq, a_buf, W1f, outA2);
  k_h1<<<dim3(512), dim3(256), 0, stream>>>(a_buf, xq, tgt, W1f, h1);
  k_w2p<<<dim3(256), dim3(256), 0, stream>>>(h1, W2, W3, lp);
  // fused: edge softmax + S + agg + lin + x_c + hop2
  k_edgelin<<<dim3(64), dim3(256), 0, stream>>>(M_g, lp, x, linW, A_g, S_g, xcb, xq2);
  // pair g
  k_wkg<<<dim3(256), dim3(256), 0, stream>>>(xcb, Wk + 2*16384, a_buf);
  k_h1<<<dim3(512), dim3(256), 0, stream>>>(a_buf, xq2, tgt, W1f + 2*98304, h1);
  k_w2p<<<dim3(256), dim3(256), 0, stream>>>(h1, W2 + 2*32768, W3 + 2*128, lp);
  // pool + direct A2 block writes
  k_A2c<<<dim3(64), dim3(256), 0, stream>>>(lp, x, A_g, S_g, outA2, outX, outB, outP);
}

// Round 14
// 210.464 us; speedup vs baseline: 1.3488x; 1.0822x over previous
//
#include <hip/hip_runtime.h>

// B=64 batches, n=64 nodes/batch, H=128, epg=2048 edges/batch
#define KK 52
#define NKOUT 3328
#define NEG 0.01f

typedef __attribute__((ext_vector_type(8))) __bf16 bf16x8;
typedef __attribute__((ext_vector_type(16))) float floatx16;

__device__ __forceinline__ float lrelu(float v){ return v > 0.f ? v : NEG*v; }

// LDS layout for MFMA chunks: row pitch 40 bf16 (80B); XOR swizzle on 16B chunks
#define SW(r, ko) ((r)*40 + ((ko) ^ ((((r)>>3)&3) << 3)))

__device__ __forceinline__ void split_store8(const float* vv, __bf16* P0, __bf16* P1, __bf16* P2, int addr){
  bf16x8 p1, p2, p3;
  #pragma unroll
  for (int j = 0; j < 8; j++){
    __bf16 b1 = (__bf16)vv[j];
    float r1 = vv[j] - (float)b1;
    __bf16 b2 = (__bf16)r1;
    float r2 = r1 - (float)b2;
    p1[j] = b1; p2[j] = b2; p3[j] = (__bf16)r2;
  }
  *(bf16x8*)(P0 + addr) = p1;
  *(bf16x8*)(P1 + addr) = p2;
  *(bf16x8*)(P2 + addr) = p3;
}

__device__ __forceinline__ void mfma6(const __bf16* A0, const __bf16* A1, const __bf16* A2,
                                      const __bf16* B0, const __bf16* B1, const __bf16* B2,
                                      int aoff, int boff, floatx16* acc){
  bf16x8 a1 = *(const bf16x8*)(A0 + aoff);
  bf16x8 a2 = *(const bf16x8*)(A1 + aoff);
  bf16x8 a3 = *(const bf16x8*)(A2 + aoff);
  bf16x8 b1 = *(const bf16x8*)(B0 + boff);
  bf16x8 b2 = *(const bf16x8*)(B1 + boff);
  bf16x8 b3 = *(const bf16x8*)(B2 + boff);
  floatx16 c = *acc;
  c = __builtin_amdgcn_mfma_f32_32x32x16_bf16(a1,b1,c,0,0,0);
  c = __builtin_amdgcn_mfma_f32_32x32x16_bf16(a1,b2,c,0,0,0);
  c = __builtin_amdgcn_mfma_f32_32x32x16_bf16(a2,b1,c,0,0,0);
  c = __builtin_amdgcn_mfma_f32_32x32x16_bf16(a1,b3,c,0,0,0);
  c = __builtin_amdgcn_mfma_f32_32x32x16_bf16(a3,b1,c,0,0,0);
  c = __builtin_amdgcn_mfma_f32_32x32x16_bf16(a2,b2,c,0,0,0);
  *acc = c;
}

// ---- generic 64x128 MFMA GEMM core (bf16x6 fp32-faithful), batched loads + reg prefetch ----
__device__ __forceinline__ void g_gemm(const float* A0, int ldA,
                                       const float* __restrict__ W0, int ldW, int K,
                                       __bf16* pb, floatx16* oA, floatx16* oB){
  __bf16 *As0 = pb, *As1 = pb+2560, *As2 = pb+5120;
  __bf16 *Bs0 = pb+7680, *Bs1 = pb+12800, *Bs2 = pb+17920;
  int tid = threadIdx.x;
  int sar = tid >> 2, sako = (tid & 3)*8;
  int bn = tid & 127, bk = (tid >> 7)*16;
  int wv_ = tid >> 6, L = tid & 63, m = L & 31, half = L >> 5;
  int rA = 32*(wv_ & 1) + m, rB0 = (wv_ >> 1)*32 + m, rB1 = rB0 + 64;
  const float* arow = A0 + (size_t)sar*ldA;
  floatx16 accA, accB;
  #pragma unroll
  for (int i = 0; i < 16; i++){ accA[i] = 0.f; accB[i] = 0.f; }
  float ra[8], wv[16];
  {
    float4 v0 = *(const float4*)(arow + sako);
    float4 v1 = *(const float4*)(arow + sako + 4);
    ra[0]=v0.x; ra[1]=v0.y; ra[2]=v0.z; ra[3]=v0.w; ra[4]=v1.x; ra[5]=v1.y; ra[6]=v1.z; ra[7]=v1.w;
    #pragma unroll
    for (int j = 0; j < 16; j++) wv[j] = W0[(size_t)(bk + j)*ldW + bn];
  }
  for (int k0 = 0; k0 < K; k0 += 32){
    split_store8(ra, As0, As1, As2, SW(sar, sako));
    split_store8(wv,     Bs0, Bs1, Bs2, SW(bn, bk));
    split_store8(wv + 8, Bs0, Bs1, Bs2, SW(bn, bk + 8));
    __syncthreads();
    int k1 = k0 + 32;
    float ra2[8], wv2[16];
    if (k1 < K){
      float4 v0 = *(const float4*)(arow + k1 + sako);
      float4 v1 = *(const float4*)(arow + k1 + sako + 4);
      ra2[0]=v0.x; ra2[1]=v0.y; ra2[2]=v0.z; ra2[3]=v0.w; ra2[4]=v1.x; ra2[5]=v1.y; ra2[6]=v1.z; ra2[7]=v1.w;
      #pragma unroll
      for (int j = 0; j < 16; j++) wv2[j] = W0[(size_t)(k1 + bk + j)*ldW + bn];
    }
    #pragma unroll
    for (int kg = 0; kg < 2; kg++){
      int ko = kg*16 + half*8;
      mfma6(As0,As1,As2, Bs0,Bs1,Bs2, SW(rA,ko), SW(rB0,ko), &accA);
      mfma6(As0,As1,As2, Bs0,Bs1,Bs2, SW(rA,ko), SW(rB1,ko), &accB);
    }
    __syncthreads();
    if (k1 < K){
      #pragma unroll
      for (int j = 0; j < 8; j++) ra[j] = ra2[j];
      #pragma unroll
      for (int j = 0; j < 16; j++) wv[j] = wv2[j];
    }
  }
  *oA = accA; *oB = accB;
}

// ---- generic 64x64-tile MFMA GEMM core (4 waves, one 32x32 quadrant each) ----
__device__ __forceinline__ void g_gemm64(const float* __restrict__ A0, int ldA,
                                         const float* __restrict__ W0, int ldW, int K,
                                         __bf16* pb, floatx16* oC){
  __bf16 *As0 = pb, *As1 = pb+2560, *As2 = pb+5120;
  __bf16 *Bs0 = pb+7680, *Bs1 = pb+10240, *Bs2 = pb+12800;
  int tid = threadIdx.x;
  int sar = tid >> 2, sako = (tid & 3)*8;
  int bn = tid & 63, bk = (tid >> 6)*8;
  int wv_ = tid >> 6, L = tid & 63, m = L & 31, half = L >> 5;
  int rA = 32*(wv_ & 1) + m, rB = 32*(wv_ >> 1) + m;
  const float* arow = A0 + (size_t)sar*ldA;
  floatx16 acc;
  #pragma unroll
  for (int i = 0; i < 16; i++) acc[i] = 0.f;
  float ra[8], wv[8];
  {
    float4 v0 = *(const float4*)(arow + sako);
    float4 v1 = *(const float4*)(arow + sako + 4);
    ra[0]=v0.x; ra[1]=v0.y; ra[2]=v0.z; ra[3]=v0.w; ra[4]=v1.x; ra[5]=v1.y; ra[6]=v1.z; ra[7]=v1.w;
    #pragma unroll
    for (int j = 0; j < 8; j++) wv[j] = W0[(size_t)(bk + j)*ldW + bn];
  }
  for (int k0 = 0; k0 < K; k0 += 32){
    split_store8(ra, As0, As1, As2, SW(sar, sako));
    split_store8(wv, Bs0, Bs1, Bs2, SW(bn, bk));
    __syncthreads();
    int k1 = k0 + 32;
    float ra2[8], wv2[8];
    if (k1 < K){
      float4 v0 = *(const float4*)(arow + k1 + sako);
      float4 v1 = *(const float4*)(arow + k1 + sako + 4);
      ra2[0]=v0.x; ra2[1]=v0.y; ra2[2]=v0.z; ra2[3]=v0.w; ra2[4]=v1.x; ra2[5]=v1.y; ra2[6]=v1.z; ra2[7]=v1.w;
      #pragma unroll
      for (int j = 0; j < 8; j++) wv2[j] = W0[(size_t)(k1 + bk + j)*ldW + bn];
    }
    #pragma unroll
    for (int kg = 0; kg < 2; kg++){
      int ko = kg*16 + half*8;
      mfma6(As0,As1,As2, Bs0,Bs1,Bs2, SW(rA,ko), SW(rB,ko), &acc);
    }
    __syncthreads();
    if (k1 < K){
      #pragma unroll
      for (int j = 0; j < 8; j++){ ra[j] = ra2[j]; wv[j] = wv2[j]; }
    }
  }
  *oC = acc;
}

// ---- 64x64-tile W1 GEMM core (K=384, pre-folded W1f, h=[a,q,a*q] synthesized) ----
__device__ __forceinline__ void g_gemm_h64(const float* __restrict__ arow, const float* __restrict__ qrow,
                                           const float* __restrict__ W1fz, int colbase,
                                           __bf16* pb, floatx16* oC){
  __bf16 *As0 = pb, *As1 = pb+2560, *As2 = pb+5120;
  __bf16 *Bs0 = pb+7680, *Bs1 = pb+10240, *Bs2 = pb+12800;
  int tid = threadIdx.x;
  int sar = tid >> 2, sako = (tid & 3)*8;
  int bn = tid & 63, bk = (tid >> 6)*8;
  int col = colbase + bn;
  int wv_ = tid >> 6, L = tid & 63, m = L & 31, half = L >> 5;
  int rA = 32*(wv_ & 1) + m, rB = 32*(wv_ >> 1) + m;
  auto loadA = [&](int k0, float* r){
    int seg = k0 >> 7, kl = (k0 & 127) + sako;
    if (seg == 0){
      float4 a0 = *(const float4*)(arow + kl), a1 = *(const float4*)(arow + kl + 4);
      r[0]=a0.x; r[1]=a0.y; r[2]=a0.z; r[3]=a0.w; r[4]=a1.x; r[5]=a1.y; r[6]=a1.z; r[7]=a1.w;
    } else if (seg == 1){
      float4 q0 = *(const float4*)(qrow + kl), q1 = *(const float4*)(qrow + kl + 4);
      r[0]=q0.x; r[1]=q0.y; r[2]=q0.z; r[3]=q0.w; r[4]=q1.x; r[5]=q1.y; r[6]=q1.z; r[7]=q1.w;
    } else {
      float4 a0 = *(const float4*)(arow + kl), a1 = *(const float4*)(arow + kl + 4);
      float4 q0 = *(const float4*)(qrow + kl), q1 = *(const float4*)(qrow + kl + 4);
      r[0]=a0.x*q0.x; r[1]=a0.y*q0.y; r[2]=a0.z*q0.z; r[3]=a0.w*q0.w;
      r[4]=a1.x*q1.x; r[5]=a1.y*q1.y; r[6]=a1.z*q1.z; r[7]=a1.w*q1.w;
    }
  };
  auto loadB = [&](int k0, float* r){
    #pragma unroll
    for (int j = 0; j < 8; j++) r[j] = W1fz[(size_t)(k0 + bk + j)*256 + col];
  };
  floatx16 acc;
  #pragma unroll
  for (int i = 0; i < 16; i++) acc[i] = 0.f;
  float ra[8], wv[8];
  loadA(0, ra); loadB(0, wv);
  for (int k0 = 0; k0 < 384; k0 += 32){
    split_store8(ra, As0, As1, As2, SW(sar, sako));
    split_store8(wv, Bs0, Bs1, Bs2, SW(bn, bk));
    __syncthreads();
    int k1 = k0 + 32;
    float ra2[8], wv2[8];
    if (k1 < 384){ loadA(k1, ra2); loadB(k1, wv2); }
    #pragma unroll
    for (int kg = 0; kg < 2; kg++){
      int ko = kg*16 + half*8;
      mfma6(As0,As1,As2, Bs0,Bs1,Bs2, SW(rA,ko), SW(rB,ko), &acc);
    }
    __syncthreads();
    if (k1 < 384){
      #pragma unroll
      for (int j = 0; j < 8; j++){ ra[j] = ra2[j]; wv[j] = wv2[j]; }
    }
  }
  *oC = acc;
}

__device__ __forceinline__ void c_write(floatx16 accA, floatx16 accB, float* C0, int ldC, int act){
  int tid = threadIdx.x, wv_ = tid >> 6, L = tid & 63, m = L & 31, half = L >> 5;
  int rB0 = (wv_ >> 1)*32 + m, rB1 = rB0 + 64;
  int row0 = 32*(wv_ & 1) + 4*half;
  #pragma unroll
  for (int reg = 0; reg < 16; reg++){
    int row = row0 + (reg & 3) + 8*(reg >> 2);
    float va = accA[reg], vb = accB[reg];
    if (act){ va = lrelu(va); vb = lrelu(vb); }
    C0[(size_t)row*ldC + rB0] = va;
    C0[(size_t)row*ldC + rB1] = vb;
  }
}

__device__ __forceinline__ void c_write64(floatx16 acc, float* C0, int ldC, int act){
  int tid = threadIdx.x, wv_ = tid >> 6, L = tid & 63, m = L & 31, half = L >> 5;
  int col = 32*(wv_ >> 1) + m;
  int row0 = 32*(wv_ & 1) + 4*half;
  #pragma unroll
  for (int reg = 0; reg < 16; reg++){
    int row = row0 + (reg & 3) + 8*(reg >> 2);
    float v = acc[reg];
    if (act) v = lrelu(v);
    C0[(size_t)row*ldC + col] = v;
  }
}

// ---- double hop (A^T twice), A in LDS; src either global rows (ld128) or LDS (ldV); dst ld128 ----
__device__ __forceinline__ void hop2_run(const float* A, const float* VfullL, int ldV,
                                         const float* srcG, float* dstG, int dstOff,
                                         float* Vt, float* Tt, int fbeg, int fend){
  int tid = threadIdx.x;
  int tc = (tid & 31)*2, tf = (tid >> 5)*4;
  for (int f0 = fbeg; f0 < fend; f0 += 32){
    if (!VfullL){
      for (int o = tid; o < 2048; o += 256){
        int r = o >> 5, f = o & 31;
        Vt[o] = srcG[r*128 + f0 + f];
      }
      __syncthreads();
    }
    float a00,a01,a02,a03,a10,a11,a12,a13;
    a00=a01=a02=a03=a10=a11=a12=a13=0.f;
    for (int r = 0; r < 64; r++){
      float x0 = A[r*64 + tc], x1 = A[r*64 + tc + 1];
      float4 v4 = VfullL ? *(const float4*)&VfullL[r*ldV + f0 + tf]
                         : *(const float4*)&Vt[r*32 + tf];
      a00 += x0*v4.x; a01 += x0*v4.y; a02 += x0*v4.z; a03 += x0*v4.w;
      a10 += x1*v4.x; a11 += x1*v4.y; a12 += x1*v4.z; a13 += x1*v4.w;
    }
    *(float4*)&Tt[tc*32 + tf]     = make_float4(a00,a01,a02,a03);
    *(float4*)&Tt[(tc+1)*32 + tf] = make_float4(a10,a11,a12,a13);
    __syncthreads();
    a00=a01=a02=a03=a10=a11=a12=a13=0.f;
    for (int r = 0; r < 64; r++){
      float x0 = A[r*64 + tc], x1 = A[r*64 + tc + 1];
      float4 v4 = *(const float4*)&Tt[r*32 + tf];
      a00 += x0*v4.x; a01 += x0*v4.y; a02 += x0*v4.z; a03 += x0*v4.w;
      a10 += x1*v4.x; a11 += x1*v4.y; a12 += x1*v4.z; a13 += x1*v4.w;
    }
    *(float4*)(dstG + tc*128 + dstOff + f0 + tf)     = make_float4(a00,a01,a02,a03);
    *(float4*)(dstG + (tc+1)*128 + dstOff + f0 + tf) = make_float4(a10,a11,a12,a13);
    __syncthreads();
  }
}

// ===== K1: build+hop2 f-split (blk<128) || Wk-f (128..255) || W1 fold (256..319)
//          || A2 zero (320..3023) || xl = x @ linW (3024..3151) =====
__global__ __launch_bounds__(256) void k_p0(const int* __restrict__ ei, const float* __restrict__ ew,
                                            const float* __restrict__ x, const float* __restrict__ Wk,
                                            const float* __restrict__ W1, const float* __restrict__ linW,
                                            float* A_g, float* M_g, float* xq, float* a_buf, float* W1f,
                                            float* xl0, float* xl1, float* outA2){
  __shared__ __align__(16) char POOL[57856];
  float* pf = (float*)POOL;
  __bf16* pb = (__bf16*)POOL;
  int blk = blockIdx.x, tid = threadIdx.x;
  if (blk < 128){
    int b = blk >> 1, fh = blk & 1;
    float* Ws = pf; float* Mc = pf + 4096; float* dv = pf + 8192;
    for (int i = tid; i < 4096; i += 256){ Ws[i] = 0.f; Mc[i] = 0.f; }
    __syncthreads();
    const int* r0 = ei + b*2048;
    const int* c0 = ei + 64*2048 + b*2048;
    const float* w0 = ew + b*2048;
    int base = b*64;
    for (int e = tid; e < 2048; e += 256){
      int r = r0[e] - base, c = c0[e] - base;
      atomicAdd(&Ws[r*64 + c], w0[e]);
      atomicAdd(&Mc[r*64 + c], 1.f);
    }
    if (tid < 64){ atomicAdd(&Ws[tid*65], 1.f); atomicAdd(&Mc[tid*65], 1.f); }
    __syncthreads();
    if (tid < 64){
      float d = 0.f;
      for (int r = 0; r < 64; r++) d += Ws[r*64 + tid];
      dv[tid] = d > 0.f ? rsqrtf(fmaxf(d, 1e-12f)) : 0.f;
    }
    __syncthreads();
    for (int i = tid; i < 4096; i += 256){
      int r = i >> 6, c = i & 63;
      float a = dv[r]*Ws[i]*dv[c];
      Ws[i] = a;
      if (fh == 0){
        A_g[b*4096 + i] = a;
        M_g[b*4096 + i] = Mc[i];
      }
    }
    __syncthreads();
    hop2_run(Ws, nullptr, 0, x + (size_t)b*8192, xq + (size_t)b*8192, 0, pf + 8256, pf + 10304,
             fh*64, fh*64 + 64);
  } else if (blk < 256){
    int idx = blk - 128, z = idx >> 6, b = idx & 63;
    floatx16 cA, cB;
    g_gemm(x + (size_t)b*8192, 128, Wk + (size_t)z*16384, 128, 128, pb, &cA, &cB);
    c_write(cA, cB, a_buf + (size_t)z*524288 + (size_t)b*8192, 128, 0);
  } else if (blk < 320){
    // fold W1 (all 4 heads) -> W1f[head][384][256]
    int idx0 = (blk - 256)*6144;
    for (int i = tid; i < 6144; i += 256){
      int g = idx0 + i;
      int zz = g / 98304;
      int r = g - zz*98304;
      int kr = r >> 8, c = r & 255;
      const float* Wz = W1 + (size_t)zz*131072;
      float v;
      if (kr < 128)       v = Wz[kr*256 + c] + Wz[(kr + 256)*256 + c];
      else if (kr < 256)  v = Wz[kr*256 + c] - Wz[(kr + 128)*256 + c];
      else                v = Wz[(kr + 128)*256 + c];
      W1f[g] = v;
    }
  } else if (blk < 3024){
    // zero-fill full A2 region (44.3 MB); nonzero blocks overwritten later by k_A2c
    float4* p = (float4*)outA2;
    int base = (blk - 320)*1024 + tid;
    #pragma unroll
    for (int i = 0; i < 4; i++) p[base + i*256] = make_float4(0.f,0.f,0.f,0.f);
  } else {
    // xl_h = x @ linW_h (2 heads x 64 batches)
    int idx = blk - 3024, z = idx >> 6, b = idx & 63;
    floatx16 cA, cB;
    g_gemm(x + (size_t)b*8192, 128, linW + (size_t)z*16384, 128, 128, pb, &cA, &cB);
    c_write(cA, cB, (z ? xl1 : xl0) + (size_t)b*8192, 128, 0);
  }
}

// ===== K2: W1 fold GEMM (512 blocks: b,z,nq) — 64x64 tiles, 2 blocks/CU =====
__global__ __launch_bounds__(256) void k_h1(const float* __restrict__ a_buf, const float* __restrict__ q0,
                                            const float* __restrict__ tgt, const float* __restrict__ W1fp,
                                            float* h1){
  __shared__ __align__(16) char POOL[30720];
  __bf16* pb = (__bf16*)POOL;
  int blk = blockIdx.x, tid = threadIdx.x;
  int b = blk >> 3, z = (blk >> 2) & 1, nq = blk & 3;
  int sar = tid >> 2;
  const float* arow = a_buf + (size_t)z*524288 + ((size_t)b*64 + sar)*128;
  const float* qrow = z ? (tgt + (size_t)b*128) : (q0 + ((size_t)b*64 + sar)*128);
  floatx16 c;
  g_gemm_h64(arow, qrow, W1fp + (size_t)z*98304, nq*64, pb, &c);
  c_write64(c, h1 + (size_t)z*1048576 + (size_t)b*16384 + nq*64, 256, 1);
}

// ===== K3: W2 partial-logit GEMM (256 blocks: b,z,nh) — 64x64 tiles, partial W3 dot =====
__global__ __launch_bounds__(256) void k_w2p(const float* __restrict__ h1, const float* __restrict__ W2,
                                             const float* __restrict__ W3, float* __restrict__ lp){
  __shared__ __align__(16) char POOL[30720];
  __shared__ float lgp[128];
  __bf16* pb = (__bf16*)POOL;
  int blk = blockIdx.x, tid = threadIdx.x;
  int b = blk >> 2, z = (blk >> 1) & 1, nh = blk & 1;
  floatx16 c;
  g_gemm64(h1 + (size_t)z*1048576 + (size_t)b*16384, 256,
           W2 + (size_t)z*32768 + nh*64, 128, 256, pb, &c);
  int wv_ = tid >> 6, L = tid & 63, m = L & 31, half = L >> 5;
  int col = 32*(wv_ >> 1) + m;
  float w = W3[z*128 + nh*64 + col];
  float v[16];
  #pragma unroll
  for (int reg = 0; reg < 16; reg++) v[reg] = lrelu(c[reg])*w;
  #pragma unroll
  for (int off = 1; off < 32; off <<= 1)
    #pragma unroll
    for (int reg = 0; reg < 16; reg++) v[reg] += __shfl_xor(v[reg], off);
  if (m == 0){
    #pragma unroll
    for (int reg = 0; reg < 16; reg++) lgp[wv_*32 + half*16 + reg] = v[reg];
  }
  __syncthreads();
  if (tid < 64){
    int row = tid, rh = row >> 5, rem = row & 31;
    int hf = (rem >> 2) & 1, rg = (rem & 3) + 4*(rem >> 3);
    float p = lgp[rh*32 + hf*16 + rg] + lgp[(rh + 2)*32 + hf*16 + rg];
    lp[(z*2 + nh)*4096 + b*64 + row] = p;
  }
}

// ===== K4: edge softmax + S + y=Ew^T xl + x_c + hop2, f-split (128 blocks: b, fh) =====
__global__ __launch_bounds__(256) void k_edgehop(const float* __restrict__ M_g, const float* __restrict__ lp,
                                                 const float* __restrict__ x, const float* __restrict__ xl0g,
                                                 const float* __restrict__ xl1g, const float* __restrict__ A_g,
                                                 float* S_g, float* xcb, float* xq2){
  __shared__ __align__(16) float Mc[4096];     // multiplicity -> Ew
  __shared__ __align__(16) float xh[4096];     // x half -> x_c half (in-place)
  __shared__ __align__(16) float xl0h[4096];
  __shared__ __align__(16) float xl1h[4096];
  __shared__ __align__(16) float Ab[4096];
  __shared__ __align__(16) float Tt[2048];
  __shared__ float f1s[64], f2s[64];
  int blk = blockIdx.x, b = blk >> 1, fh = blk & 1, tid = threadIdx.x;
  int foff = fh*64;
  for (int i = tid; i < 4096; i += 256) Mc[i] = M_g[b*4096 + i];
  for (int o = tid*4; o < 4096; o += 1024){
    int r = o >> 6, f = o & 63;
    *(float4*)&xh[o]   = *(const float4*)(x    + (size_t)b*8192 + r*128 + foff + f);
    *(float4*)&xl0h[o] = *(const float4*)(xl0g + (size_t)b*8192 + r*128 + foff + f);
    *(float4*)&xl1h[o] = *(const float4*)(xl1g + (size_t)b*8192 + r*128 + foff + f);
  }
  if (tid < 128){
    int z = tid >> 6, r = tid & 63;
    float d = lp[(z*2)*4096 + b*64 + r] + lp[(z*2 + 1)*4096 + b*64 + r];
    float l = lrelu(d);
    float mx = l;
    #pragma unroll
    for (int off = 32; off; off >>= 1) mx = fmaxf(mx, __shfl_xor(mx, off));
    float e = expf(l - mx);
    float s = e;
    #pragma unroll
    for (int off = 32; off; off >>= 1) s += __shfl_xor(s, off);
    (z ? f2s : f1s)[r] = e/s;
  }
  __syncthreads();
  {
    int c = tid >> 2, sub = tid & 3;
    float m = -1e30f;
    for (int r = sub; r < 64; r += 4)
      if (Mc[r*64 + c] > 0.f) m = fmaxf(m, lrelu(f1s[c] + f2s[r]));
    m = fmaxf(m, __shfl_xor(m, 1));
    m = fmaxf(m, __shfl_xor(m, 2));
    float s = 0.f;
    for (int r = sub; r < 64; r += 4){
      float mc = Mc[r*64 + c];
      if (mc > 0.f) s += mc*expf(lrelu(f1s[c] + f2s[r]) - m);
    }
    s += __shfl_xor(s, 1);
    s += __shfl_xor(s, 2);
    for (int r = sub; r < 64; r += 4){
      float mc = Mc[r*64 + c];
      float v = 0.f;
      if (mc > 0.f) v = mc*expf(lrelu(f1s[c] + f2s[r]) - m)/s;
      Mc[r*64 + c] = v;
    }
  }
  __syncthreads();
  if (fh == 0)
    for (int i = tid; i < 4096; i += 256) S_g[b*4096 + i] = Mc[i];
  // y_h[c][f] = sum_r Ew[r][c] * xl_h[r][f]; then x_c in-place into xh
  {
    int tc = (tid & 15)*4, tf = (tid >> 4)*4;
    float a0[4][4], a1[4][4];
    #pragma unroll
    for (int i = 0; i < 4; i++)
      #pragma unroll
      for (int j = 0; j < 4; j++){ a0[i][j] = 0.f; a1[i][j] = 0.f; }
    for (int r = 0; r < 64; r++){
      float4 e4 = *(const float4*)&Mc[r*64 + tc];
      float4 p0 = *(const float4*)&xl0h[r*64 + tf];
      float4 p1 = *(const float4*)&xl1h[r*64 + tf];
      float e_[4] = {e4.x,e4.y,e4.z,e4.w};
      float p0_[4] = {p0.x,p0.y,p0.z,p0.w};
      float p1_[4] = {p1.x,p1.y,p1.z,p1.w};
      #pragma unroll
      for (int ci = 0; ci < 4; ci++)
        #pragma unroll
        for (int fj = 0; fj < 4; fj++){
          a0[ci][fj] += e_[ci]*p0_[fj];
          a1[ci][fj] += e_[ci]*p1_[fj];
        }
    }
    __syncthreads();
    #pragma unroll
    for (int ci = 0; ci < 4; ci++){
      int c = tc + ci;
      float4 xv = *(const float4*)&xh[c*64 + tf];
      float4 o;
      o.x = 0.5f*(lrelu(xv.x + a0[ci][0]) + lrelu(xv.x + a1[ci][0]));
      o.y = 0.5f*(lrelu(xv.y + a0[ci][1]) + lrelu(xv.y + a1[ci][1]));
      o.z = 0.5f*(lrelu(xv.z + a0[ci][2]) + lrelu(xv.z + a1[ci][2]));
      o.w = 0.5f*(lrelu(xv.w + a0[ci][3]) + lrelu(xv.w + a1[ci][3]));
      *(float4*)&xh[c*64 + tf] = o;
      *(float4*)(xcb + (size_t)b*8192 + c*128 + foff + tf) = o;
    }
  }
  for (int i = tid*4; i < 4096; i += 1024)
    *(float4*)&Ab[i] = *(const float4*)(A_g + b*4096 + i);
  __syncthreads();
  hop2_run(Ab, xh, 64, nullptr, xq2 + (size_t)b*8192, foff, Tt, Tt, 0, 64);
}

// ===== K5: Wk pair g (256 blocks: b,z,nh) — 64x64 tiles =====
__global__ __launch_bounds__(256) void k_wkg(const float* __restrict__ xcb, const float* __restrict__ Wkg,
                                             float* a_buf){
  __shared__ __align__(16) char POOL[30720];
  __bf16* pb = (__bf16*)POOL;
  int blk = blockIdx.x;
  int b = blk >> 2, z = (blk >> 1) & 1, nh = blk & 1;
  floatx16 c;
  g_gemm64(xcb + (size_t)b*8192, 128, Wkg + (size_t)z*16384 + nh*64, 128, 128, pb, &c);
  c_write64(c, a_buf + (size_t)z*524288 + (size_t)b*8192 + nh*64, 128, 0);
}

// ===== K6: pool (softmaxes from lp + bitonic top-52 + x_out) + direct A2 block writes (64 blocks) =====
__global__ __launch_bounds__(256) void k_A2c(const float* __restrict__ lp, const float* __restrict__ x,
                                             const float* __restrict__ A_g, const float* __restrict__ S_g,
                                             float* outA2, float* outX, float* outB, float* outP){
  __shared__ __align__(16) float At[64*68];
  __shared__ __align__(16) float Sp[64*56];
  __shared__ __align__(16) float Tq[64*56];
  __shared__ int pi[64];
  __shared__ float pv[64];
  int b = blockIdx.x, tid = threadIdx.x;
  if (tid < 64){
    int lane = tid;
    float f[2];
    #pragma unroll
    for (int z = 0; z < 2; z++){
      float d = lp[(z*2)*4096 + b*64 + lane] + lp[(z*2 + 1)*4096 + b*64 + lane];
      float l = lrelu(d);
      float mx = l;
      #pragma unroll
      for (int off = 32; off; off >>= 1) mx = fmaxf(mx, __shfl_xor(mx, off));
      float e = expf(l - mx);
      float sm = e;
      #pragma unroll
      for (int off = 32; off; off >>= 1) sm += __shfl_xor(sm, off);
      f[z] = e/sm;
    }
    float l = f[0] + f[1];
    float m = l;
    #pragma unroll
    for (int off = 32; off; off >>= 1) m = fmaxf(m, __shfl_xor(m, off));
    float e = expf(l - m);
    float sm = e;
    #pragma unroll
    for (int off = 32; off; off >>= 1) sm += __shfl_xor(sm, off);
    float v = e/sm;
    int idx = lane;
    #pragma unroll
    for (int k = 2; k <= 64; k <<= 1){
      #pragma unroll
      for (int j = k >> 1; j > 0; j >>= 1){
        float ov = __shfl_xor(v, j);
        int   oi = __shfl_xor(idx, j);
        bool ascBlock = (lane & k) == 0;
        bool iAmLow   = (lane & j) == 0;
        bool otherPrec = (ov > v) || (ov == v && oi < idx);
        bool take = (ascBlock == iAmLow) ? otherPrec : !otherPrec;
        if (take){ v = ov; idx = oi; }
      }
    }
    pi[lane] = idx; pv[lane] = v;
    if (lane < KK){
      outB[b*KK + lane] = (float)b;
      outP[b*KK + lane] = (float)(b*64 + idx);
    }
  }
  __syncthreads();
  for (int o = tid*4; o < KK*128; o += 1024){
    int j = o >> 7, f = o & 127;
    float4 xv = *(const float4*)(x + ((size_t)b*64 + pi[j])*128 + f);
    float sv = pv[j];
    *(float4*)(outX + (size_t)b*KK*128 + o) = make_float4(xv.x*sv, xv.y*sv, xv.z*sv, xv.w*sv);
  }
  for (int idx = tid; idx < 4096; idx += 256){
    int i = idx >> 6, k = idx & 63;
    At[k*68 + i] = A_g[b*4096 + idx];
  }
  for (int idx = tid; idx < 4096; idx += 256){
    int k = idx >> 6, t = idx & 63;
    if (t < 56) Sp[k*56 + t] = (t < KK) ? S_g[b*4096 + k*64 + pi[t]] : 0.f;
  }
  __syncthreads();
  if (tid < 224){
    int i0 = (tid/14)*4, t0 = (tid % 14)*4;
    float acc[4][4];
    #pragma unroll
    for (int a = 0; a < 4; a++)
      #pragma unroll
      for (int c = 0; c < 4; c++) acc[a][c] = 0.f;
    for (int k = 0; k < 64; k++){
      float4 a4 = *(const float4*)&At[k*68 + i0];
      float4 s4 = *(const float4*)&Sp[k*56 + t0];
      float a_[4] = {a4.x,a4.y,a4.z,a4.w};
      float s_[4] = {s4.x,s4.y,s4.z,s4.w};
      #pragma unroll
      for (int ii = 0; ii < 4; ii++)
        #pragma unroll
        for (int tt = 0; tt < 4; tt++) acc[ii][tt] += a_[ii]*s_[tt];
    }
    #pragma unroll
    for (int ii = 0; ii < 4; ii++)
      *(float4*)&Tq[(i0+ii)*56 + t0] = make_float4(acc[ii][0],acc[ii][1],acc[ii][2],acc[ii][3]);
  }
  __syncthreads();
  if (tid < 169){
    int a0 = (tid/13)*4, t0 = (tid % 13)*4;
    float acc[4][4];
    #pragma unroll
    for (int a = 0; a < 4; a++)
      #pragma unroll
      for (int c = 0; c < 4; c++) acc[a][c] = 0.f;
    for (int i = 0; i < 64; i++){
      float4 s4 = *(const float4*)&Sp[i*56 + a0];
      float4 t4 = *(const float4*)&Tq[i*56 + t0];
      float s_[4] = {s4.x,s4.y,s4.z,s4.w};
      float t_[4] = {t4.x,t4.y,t4.z,t4.w};
      #pragma unroll
      for (int aa = 0; aa < 4; aa++)
        #pragma unroll
        for (int tt = 0; tt < 4; tt++) acc[aa][tt] += s_[aa]*t_[tt];
    }
    #pragma unroll
    for (int aa = 0; aa < 4; aa++){
      int a = a0 + aa;
      float4 o;
      o.x = (a == t0    ) ? 1.f : acc[aa][0];
      o.y = (a == t0 + 1) ? 1.f : acc[aa][1];
      o.z = (a == t0 + 2) ? 1.f : acc[aa][2];
      o.w = (a == t0 + 3) ? 1.f : acc[aa][3];
      *(float4*)(outA2 + (size_t)(b*KK + a)*NKOUT + b*KK + t0) = o;
    }
  }
}

extern "C" void kernel_launch(void* const* d_in, const int* in_sizes, int n_in,
                              void* d_out, int out_size, void* d_ws, size_t ws_size,
                              hipStream_t stream){
  const float* x    = (const float*)d_in[0];
  const int*   ei   = (const int*)d_in[1];
  const float* ew   = (const float*)d_in[2];
  const float* tgt  = (const float*)d_in[3];
  const float* Wk   = (const float*)d_in[5];
  const float* W1   = (const float*)d_in[6];
  const float* W2   = (const float*)d_in[7];
  const float* W3   = (const float*)d_in[8];
  const float* linW = (const float*)d_in[9];
  float* out = (float*)d_out;

  float* wf   = (float*)d_ws;
  float* A_g  = wf;
  float* M_g  = wf + 262144;
  float* S_g  = wf + 524288;
  float* xq   = wf + 786432;
  float* xq2  = wf + 1310720;
  float* xl0  = wf + 1835008;   // 524288 (old aggb slot)
  float* xcb  = wf + 2359296;
  float* a_buf= wf + 2883584;   // 2 x 524288
  float* h1   = wf + 3932160;   // 2 x 1048576
  float* lp   = wf + 6029312;   // 4 x 4096 partial logits
  float* W1f  = wf + 6045696;   // 4 x 98304 = 393216
  float* xl1  = wf + 6438912;   // 524288

  float* outX  = out;
  float* outA2 = out + 425984;
  float* outB  = out + 425984 + 11075584;
  float* outP  = outB + NKOUT;

  // pair f (+ W1 pre-fold + A2 zero-fill + xl precompute in spare blocks)
  k_p0<<<dim3(3152), dim3(256), 0, stream>>>(ei, ew, x, Wk, W1, linW, A_g, M_g, xq, a_buf, W1f,
                                             xl0, xl1, outA2);
  k_h1<<<dim3(512), dim3(256), 0, stream>>>(a_buf, xq, tgt, W1f, h1);
  k_w2p<<<dim3(256), dim3(256), 0, stream>>>(h1, W2, W3, lp);
  // fused edge softmax + S + y=Ew^T xl + x_c + hop2 (f-split, 128 blocks)
  k_edgehop<<<dim3(128), dim3(256), 0, stream>>>(M_g, lp, x, xl0, xl1, A_g, S_g, xcb, xq2);
  // pair g
  k_wkg<<<dim3(256), dim3(256), 0, stream>>>(xcb, Wk + 2*16384, a_buf);
  k_h1<<<dim3(512), dim3(256), 0, stream>>>(a_buf, xq2, tgt, W1f + 2*98304, h1);
  k_w2p<<<dim3(256), dim3(256), 0, stream>>>(h1, W2 + 2*32768, W3 + 2*128, lp);
  // pool + direct A2 block writes
  k_A2c<<<dim3(64), dim3(256), 0, stream>>>(lp, x, A_g, S_g, outA2, outX, outB, outP);
}